// Round 1
// baseline (1078.850 us; speedup 1.0000x reference)
//
#include <hip/hip_runtime.h>
#include <hip/hip_bf16.h>

#define N_NODES 50000
#define N_EDGES 800000
#define ET (N_EDGES + N_NODES)   // edges + self loops
#define D 128
#define BN_EPS 1e-5f

// ---------------------------------------------------------------------------
// degree count: deg[dst[e]] += 1  (accumulated as float in dinv buffer)
__global__ void deg_count(const int* __restrict__ dst, float* __restrict__ deg, int E) {
    int e = blockIdx.x * blockDim.x + threadIdx.x;
    if (e < E) atomicAdd(&deg[dst[e]], 1.0f);
}

// dinv[i] = rsqrt(deg[i] + 1)   (+1 = self loop)
__global__ void finalize_dinv(float* __restrict__ deg, int n) {
    int i = blockIdx.x * blockDim.x + threadIdx.x;
    if (i < n) deg[i] = rsqrtf(deg[i] + 1.0f);
}

// ---------------------------------------------------------------------------
// C[N x 128] = X[N x 128] @ W[128 x 128], f32, LDS-tiled.
// Block: 256 threads, 64 rows per block. Whole W (64 KB) + X tile (32 KB) in LDS.
__global__ __launch_bounds__(256) void gemm128(const float* __restrict__ X,
                                               const float* __restrict__ W,
                                               float* __restrict__ C, int nrows) {
    __shared__ float Xs[64][128];
    __shared__ float Ws[128][128];
    const int tid  = threadIdx.x;
    const int row0 = blockIdx.x * 64;

    // stage W: 4096 float4, 16 per thread (coalesced)
    const float4* W4  = (const float4*)W;
    float4*       Ws4 = (float4*)&Ws[0][0];
#pragma unroll
    for (int i = 0; i < 16; ++i) Ws4[tid + 256 * i] = W4[tid + 256 * i];

    // stage X tile: 2048 float4, 8 per thread (coalesced; OOB rows -> 0)
    const float4* X4  = (const float4*)X;
    float4*       Xs4 = (float4*)&Xs[0][0];
#pragma unroll
    for (int i = 0; i < 8; ++i) {
        int idx  = tid + 256 * i;       // float4 index in tile (32 per row)
        int r    = idx >> 5;
        int grow = row0 + r;
        float4 v = make_float4(0.f, 0.f, 0.f, 0.f);
        if (grow < nrows) v = X4[grow * 32 + (idx & 31)];
        Xs4[idx] = v;
    }
    __syncthreads();

    const int rg = tid >> 5;        // 0..7  -> rows r0..r0+7
    const int cg = tid & 31;        // 0..31 -> cols cg + 32*j
    const int r0 = rg * 8;
    float acc[8][4] = {};

    for (int k4 = 0; k4 < 32; ++k4) {
        float4 xa[8];
#pragma unroll
        for (int i = 0; i < 8; ++i) xa[i] = *(const float4*)&Xs[r0 + i][k4 * 4];
#pragma unroll
        for (int kk = 0; kk < 4; ++kk) {
            const int k = k4 * 4 + kk;
            float wb[4];
#pragma unroll
            for (int j = 0; j < 4; ++j) wb[j] = Ws[k][cg + 32 * j];
#pragma unroll
            for (int i = 0; i < 8; ++i) {
                float xv = (kk == 0) ? xa[i].x : (kk == 1) ? xa[i].y
                                               : (kk == 2) ? xa[i].z : xa[i].w;
#pragma unroll
                for (int j = 0; j < 4; ++j) acc[i][j] += xv * wb[j];
            }
        }
    }

#pragma unroll
    for (int i = 0; i < 8; ++i) {
        int grow = row0 + r0 + i;
        if (grow < nrows) {
#pragma unroll
            for (int j = 0; j < 4; ++j) C[grow * D + cg + 32 * j] = acc[i][j];
        }
    }
}

// ---------------------------------------------------------------------------
// out[dst] += H[src] * dinv[src]*dinv[dst], over E edges + N self loops.
// one thread per (edge, feature)
__global__ void scatter_add(const float* __restrict__ H, const int* __restrict__ src,
                            const int* __restrict__ dst, const float* __restrict__ dinv,
                            float* __restrict__ out) {
    int gid = blockIdx.x * blockDim.x + threadIdx.x;
    int e = gid >> 7;
    int f = gid & 127;
    if (e >= ET) return;
    int s, d;
    if (e < N_EDGES) { s = src[e]; d = dst[e]; }
    else             { s = d = e - N_EDGES; }
    float norm = dinv[s] * dinv[d];
    atomicAdd(&out[d * D + f], H[s * D + f] * norm);
}

// ---------------------------------------------------------------------------
// per-feature sum and sum-of-squares (sums[0..127]=sum, sums[128..255]=sumsq)
__global__ __launch_bounds__(256) void bn_reduce(const float* __restrict__ X,
                                                 float* __restrict__ sums, int n) {
    int f    = threadIdx.x & 127;
    int half = threadIdx.x >> 7;
    float s = 0.f, q = 0.f;
    for (int r = blockIdx.x * 2 + half; r < n; r += gridDim.x * 2) {
        float v = X[r * D + f];
        s += v;
        q += v * v;
    }
    atomicAdd(&sums[f], s);
    atomicAdd(&sums[128 + f], q);
}

// BN (training-mode, biased var) + PReLU
__global__ void bn_prelu(const float* __restrict__ X, const float* __restrict__ sums,
                         const float* __restrict__ gamma, const float* __restrict__ beta,
                         const float* __restrict__ a, float* __restrict__ out, int total,
                         float invN) {
    int idx = blockIdx.x * blockDim.x + threadIdx.x;
    if (idx >= total) return;
    int f      = idx & 127;
    float mean = sums[f] * invN;
    float var  = sums[128 + f] * invN - mean * mean;
    float sc   = rsqrtf(var + BN_EPS) * gamma[f];
    float y    = (X[idx] - mean) * sc + beta[f];
    float av   = a[0];
    out[idx]   = (y >= 0.f) ? y : av * y;
}

// ---------------------------------------------------------------------------
extern "C" void kernel_launch(void* const* d_in, const int* in_sizes, int n_in,
                              void* d_out, int out_size, void* d_ws, size_t ws_size,
                              hipStream_t stream) {
    const float* x     = (const float*)d_in[0];
    const int*   edges = (const int*)d_in[1];   // [2, E]: src then dst
    const float* W1    = (const float*)d_in[2];
    // b1 = d_in[3] : cancels under BN (per-feature constant shift) -> skipped
    const float* gamma1 = (const float*)d_in[4];
    const float* beta1  = (const float*)d_in[5];
    const float* a1     = (const float*)d_in[6];
    const float* W2     = (const float*)d_in[7];
    // b2 = d_in[8] : skipped (same reason)
    const float* gamma2 = (const float*)d_in[9];
    const float* beta2  = (const float*)d_in[10];
    const float* a2     = (const float*)d_in[11];

    const int* src = edges;
    const int* dst = edges + N_EDGES;

    float* O = (float*)d_out;                 // ping-pong buffer / final output
    float* A    = (float*)d_ws;               // 6.4M floats (25.6 MB)
    float* dinv = A + (size_t)N_NODES * D;    // 50000 floats
    float* sums = dinv + N_NODES;             // 256 floats

    const int total   = N_NODES * D;          // 6,400,000
    const float invN  = 1.0f / (float)N_NODES;

    const int degGrid  = (N_EDGES + 255) / 256;
    const int nGrid    = (N_NODES + 255) / 256;
    const int gemmGrid = (N_NODES + 63) / 64;
    const int scatGrid = (ET * D + 255) / 256;  // 425000
    const int bnGrid   = (total + 255) / 256;

    // --- degrees -> dinv ---
    hipMemsetAsync(dinv, 0, N_NODES * sizeof(float), stream);
    deg_count<<<degGrid, 256, 0, stream>>>(dst, dinv, N_EDGES);
    finalize_dinv<<<nGrid, 256, 0, stream>>>(dinv, N_NODES);

    // --- layer 1 ---
    gemm128<<<gemmGrid, 256, 0, stream>>>(x, W1, A, N_NODES);            // A = x @ W1
    hipMemsetAsync(O, 0, (size_t)total * sizeof(float), stream);
    scatter_add<<<scatGrid, 256, 0, stream>>>(A, src, dst, dinv, O);     // O = agg1
    hipMemsetAsync(sums, 0, 256 * sizeof(float), stream);
    bn_reduce<<<512, 256, 0, stream>>>(O, sums, N_NODES);
    bn_prelu<<<bnGrid, 256, 0, stream>>>(O, sums, gamma1, beta1, a1, A, total, invN); // A = y1

    // --- layer 2 ---
    gemm128<<<gemmGrid, 256, 0, stream>>>(A, W2, O, N_NODES);            // O = y1 @ W2
    hipMemsetAsync(A, 0, (size_t)total * sizeof(float), stream);
    scatter_add<<<scatGrid, 256, 0, stream>>>(O, src, dst, dinv, A);     // A = agg2
    hipMemsetAsync(sums, 0, 256 * sizeof(float), stream);
    bn_reduce<<<512, 256, 0, stream>>>(A, sums, N_NODES);
    bn_prelu<<<bnGrid, 256, 0, stream>>>(A, sums, gamma2, beta2, a2, O, total, invN); // O = out
}

// Round 2
// 782.892 us; speedup vs baseline: 1.3780x; 1.3780x over previous
//
#include <hip/hip_runtime.h>
#include <hip/hip_bf16.h>

#define N_NODES 50000
#define N_EDGES 800000
#define D 128
#define BN_EPS 1e-5f

// ---------------------------------------------------------------------------
// in-degree count (int atomics)
__global__ void deg_count(const int* __restrict__ dst, int* __restrict__ cnt) {
    int e = blockIdx.x * blockDim.x + threadIdx.x;
    if (e < N_EDGES) atomicAdd(&cnt[dst[e]], 1);
}

// dinv[i] = rsqrt(cnt[i] + 1)   (+1 = self loop)
__global__ void finalize_dinv(const int* __restrict__ cnt, float* __restrict__ dinv) {
    int i = blockIdx.x * blockDim.x + threadIdx.x;
    if (i < N_NODES) dinv[i] = rsqrtf((float)cnt[i] + 1.0f);
}

// single-block exclusive scan of cnt[0..N) -> row_ptr, cursor
__global__ __launch_bounds__(256) void scan_csr(const int* __restrict__ cnt,
                                                int* __restrict__ row_ptr,
                                                int* __restrict__ cursor) {
    __shared__ int part[257];
    const int t = threadIdx.x;
    const int C = (N_NODES + 255) / 256;   // 196
    int beg = t * C, end = min(beg + C, N_NODES);
    int s = 0;
    for (int i = beg; i < end; ++i) s += cnt[i];
    part[t + 1] = s;
    __syncthreads();
    if (t == 0) {
        part[0] = 0;
        for (int i = 1; i <= 256; ++i) part[i] += part[i - 1];
    }
    __syncthreads();
    int base = part[t];
    for (int i = beg; i < end; ++i) {
        row_ptr[i] = base;
        cursor[i]  = base;
        base += cnt[i];
    }
    if (t == 255) row_ptr[N_NODES] = N_EDGES;
}

__global__ void csr_fill(const int* __restrict__ src, const int* __restrict__ dst,
                         int* __restrict__ cursor, int* __restrict__ col) {
    int e = blockIdx.x * blockDim.x + threadIdx.x;
    if (e < N_EDGES) {
        int d = dst[e];
        int p = atomicAdd(&cursor[d], 1);
        col[p] = src[e];
    }
}

// ---------------------------------------------------------------------------
// C[N x 128] = act(X)[N x 128] @ W[128 x 128] * dinv[row]
// BN_IN: act = PReLU(BN(x; sums, gamma, beta, a)) applied while staging X.
template <bool BN_IN>
__global__ __launch_bounds__(256) void gemm128(const float* __restrict__ X,
                                               const float* __restrict__ W,
                                               float* __restrict__ C,
                                               const float* __restrict__ dinv,
                                               const float* __restrict__ sums,
                                               const float* __restrict__ gamma,
                                               const float* __restrict__ beta,
                                               const float* __restrict__ a,
                                               int nrows) {
    __shared__ float Xs[64][128];
    __shared__ float Ws[128][128];
    const int tid  = threadIdx.x;
    const int row0 = blockIdx.x * 64;
    const float invN = 1.0f / (float)N_NODES;

    // stage W: 4096 float4, 16 per thread (coalesced)
    const float4* W4  = (const float4*)W;
    float4*       Ws4 = (float4*)&Ws[0][0];
#pragma unroll
    for (int i = 0; i < 16; ++i) Ws4[tid + 256 * i] = W4[tid + 256 * i];

    // stage X tile: 2048 float4, 8 per thread (coalesced; OOB rows -> 0)
    const float4* X4  = (const float4*)X;
    float4*       Xs4 = (float4*)&Xs[0][0];
#pragma unroll
    for (int i = 0; i < 8; ++i) {
        int idx  = tid + 256 * i;       // float4 index in tile (32 per row)
        int r    = idx >> 5;
        int grow = row0 + r;
        float4 v = make_float4(0.f, 0.f, 0.f, 0.f);
        if (grow < nrows) {
            v = X4[grow * 32 + (idx & 31)];
            if (BN_IN) {
                const int f0 = (idx & 31) * 4;
                const float av = a[0];
                float* vp = (float*)&v;
#pragma unroll
                for (int c = 0; c < 4; ++c) {
                    int f = f0 + c;
                    float mean = sums[f] * invN;
                    float var  = sums[128 + f] * invN - mean * mean;
                    float sc   = rsqrtf(var + BN_EPS) * gamma[f];
                    float y    = (vp[c] - mean) * sc + beta[f];
                    vp[c]      = (y >= 0.f) ? y : av * y;
                }
            }
        }
        Xs4[idx] = v;
    }
    __syncthreads();

    const int rg = tid >> 5;        // 0..7  -> rows r0..r0+7
    const int cg = tid & 31;        // 0..31 -> cols cg + 32*j
    const int r0 = rg * 8;
    float acc[8][4] = {};

    for (int k4 = 0; k4 < 32; ++k4) {
        float4 xa[8];
#pragma unroll
        for (int i = 0; i < 8; ++i) xa[i] = *(const float4*)&Xs[r0 + i][k4 * 4];
#pragma unroll
        for (int kk = 0; kk < 4; ++kk) {
            const int k = k4 * 4 + kk;
            float wb[4];
#pragma unroll
            for (int j = 0; j < 4; ++j) wb[j] = Ws[k][cg + 32 * j];
#pragma unroll
            for (int i = 0; i < 8; ++i) {
                float xv = (kk == 0) ? xa[i].x : (kk == 1) ? xa[i].y
                                               : (kk == 2) ? xa[i].z : xa[i].w;
#pragma unroll
                for (int j = 0; j < 4; ++j) acc[i][j] += xv * wb[j];
            }
        }
    }

#pragma unroll
    for (int i = 0; i < 8; ++i) {
        int grow = row0 + r0 + i;
        if (grow < nrows) {
            float dv = dinv[grow];
#pragma unroll
            for (int j = 0; j < 4; ++j) C[grow * D + cg + 32 * j] = acc[i][j] * dv;
        }
    }
}

// ---------------------------------------------------------------------------
// pull-aggregate: out[d] = dinv[d] * (Σ_{s in in(d)} H'[s] + H'[d])
// one wave per node (stride loop); lane owns features {2l, 2l+1} as float2.
__global__ __launch_bounds__(256) void pull_agg(const float* __restrict__ H,
                                                const int* __restrict__ row_ptr,
                                                const int* __restrict__ col,
                                                const float* __restrict__ dinv,
                                                float* __restrict__ out) {
    const int lane   = threadIdx.x & 63;
    const int wave   = (blockIdx.x * blockDim.x + threadIdx.x) >> 6;
    const int nwaves = (gridDim.x * blockDim.x) >> 6;
    const float2* H2   = (const float2*)H;
    float2*       out2 = (float2*)out;

    for (int d = wave; d < N_NODES; d += nwaves) {
        const int beg = row_ptr[d];
        const int end = row_ptr[d + 1];
        float2 acc = H2[(size_t)d * 64 + lane];          // self loop
        for (int j = beg; j < end; ++j) {
            int s = col[j];
            float2 v = H2[(size_t)s * 64 + lane];
            acc.x += v.x;
            acc.y += v.y;
        }
        float dv = dinv[d];
        acc.x *= dv;
        acc.y *= dv;
        out2[(size_t)d * 64 + lane] = acc;
    }
}

// ---------------------------------------------------------------------------
// per-feature sum and sum-of-squares (sums[0..127]=sum, sums[128..255]=sumsq)
__global__ __launch_bounds__(256) void bn_reduce(const float* __restrict__ X,
                                                 float* __restrict__ sums, int n) {
    int f    = threadIdx.x & 127;
    int half = threadIdx.x >> 7;
    float s = 0.f, q = 0.f;
    for (int r = blockIdx.x * 2 + half; r < n; r += gridDim.x * 2) {
        float v = X[r * D + f];
        s += v;
        q += v * v;
    }
    atomicAdd(&sums[f], s);
    atomicAdd(&sums[128 + f], q);
}

// BN (training-mode, biased var) + PReLU, in-place safe
__global__ void bn_prelu(const float* __restrict__ X, const float* __restrict__ sums,
                         const float* __restrict__ gamma, const float* __restrict__ beta,
                         const float* __restrict__ a, float* __restrict__ out, int total,
                         float invN) {
    int idx = blockIdx.x * blockDim.x + threadIdx.x;
    if (idx >= total) return;
    int f      = idx & 127;
    float mean = sums[f] * invN;
    float var  = sums[128 + f] * invN - mean * mean;
    float sc   = rsqrtf(var + BN_EPS) * gamma[f];
    float y    = (X[idx] - mean) * sc + beta[f];
    float av   = a[0];
    out[idx]   = (y >= 0.f) ? y : av * y;
}

// ---------------------------------------------------------------------------
extern "C" void kernel_launch(void* const* d_in, const int* in_sizes, int n_in,
                              void* d_out, int out_size, void* d_ws, size_t ws_size,
                              hipStream_t stream) {
    const float* x      = (const float*)d_in[0];
    const int*   edges  = (const int*)d_in[1];   // [2, E]: src then dst
    const float* W1     = (const float*)d_in[2];
    // b1 = d_in[3] cancels under training-mode BN -> skipped
    const float* gamma1 = (const float*)d_in[4];
    const float* beta1  = (const float*)d_in[5];
    const float* a1     = (const float*)d_in[6];
    const float* W2     = (const float*)d_in[7];
    // b2 = d_in[8] skipped (same reason)
    const float* gamma2 = (const float*)d_in[9];
    const float* beta2  = (const float*)d_in[10];
    const float* a2     = (const float*)d_in[11];

    const int* src = edges;
    const int* dst = edges + N_EDGES;

    float* O = (float*)d_out;                       // [N,128] ping-pong / final
    char*  ws = (char*)d_ws;
    float* A       = (float*)ws;                    // 6.4M floats (25.6 MB)
    ws += (size_t)N_NODES * D * sizeof(float);
    float* dinv    = (float*)ws;  ws += N_NODES * sizeof(float);
    float* sums    = (float*)ws;  ws += 256 * sizeof(float);
    int*   cnt     = (int*)ws;    ws += N_NODES * sizeof(int);
    int*   cursor  = (int*)ws;    ws += N_NODES * sizeof(int);
    int*   row_ptr = (int*)ws;    ws += (N_NODES + 1) * sizeof(int);
    int*   col     = (int*)ws;    ws += (size_t)N_EDGES * sizeof(int);

    const int total  = N_NODES * D;
    const float invN = 1.0f / (float)N_NODES;

    const int eGrid    = (N_EDGES + 255) / 256;
    const int nGrid    = (N_NODES + 255) / 256;
    const int gemmGrid = (N_NODES + 63) / 64;
    const int bnGrid   = (total + 255) / 256;

    // --- CSR + dinv (per launch; d_ws is re-poisoned) ---
    hipMemsetAsync(cnt, 0, N_NODES * sizeof(int), stream);
    deg_count<<<eGrid, 256, 0, stream>>>(dst, cnt);
    finalize_dinv<<<nGrid, 256, 0, stream>>>(cnt, dinv);
    scan_csr<<<1, 256, 0, stream>>>(cnt, row_ptr, cursor);
    csr_fill<<<eGrid, 256, 0, stream>>>(src, dst, cursor, col);

    // --- layer 1 ---
    gemm128<false><<<gemmGrid, 256, 0, stream>>>(x, W1, A, dinv,
                                                 nullptr, nullptr, nullptr, nullptr, N_NODES);
    pull_agg<<<1024, 256, 0, stream>>>(A, row_ptr, col, dinv, O);
    hipMemsetAsync(sums, 0, 256 * sizeof(float), stream);
    bn_reduce<<<512, 256, 0, stream>>>(O, sums, N_NODES);

    // --- layer 2 (BN1+PReLU fused into GEMM2 input staging) ---
    gemm128<true><<<gemmGrid, 256, 0, stream>>>(O, W2, A, dinv,
                                                sums, gamma1, beta1, a1, N_NODES);
    pull_agg<<<1024, 256, 0, stream>>>(A, row_ptr, col, dinv, O);
    hipMemsetAsync(sums, 0, 256 * sizeof(float), stream);
    bn_reduce<<<512, 256, 0, stream>>>(O, sums, N_NODES);
    bn_prelu<<<bnGrid, 256, 0, stream>>>(O, sums, gamma2, beta2, a2, O, total, invN);
}

// Round 3
// 624.887 us; speedup vs baseline: 1.7265x; 1.2529x over previous
//
#include <hip/hip_runtime.h>
#include <hip/hip_bf16.h>

#define N_NODES 50000
#define N_EDGES 800000
#define D 128
#define BN_EPS 1e-5f

// ---------------------------------------------------------------------------
// in-degree count (int atomics)
__global__ void deg_count(const int* __restrict__ dst, int* __restrict__ cnt) {
    int e = blockIdx.x * blockDim.x + threadIdx.x;
    if (e < N_EDGES) atomicAdd(&cnt[dst[e]], 1);
}

// dinv[i] = rsqrt(cnt[i] + 1)   (+1 = self loop)
__global__ void finalize_dinv(const int* __restrict__ cnt, float* __restrict__ dinv) {
    int i = blockIdx.x * blockDim.x + threadIdx.x;
    if (i < N_NODES) dinv[i] = rsqrtf((float)cnt[i] + 1.0f);
}

// single-block exclusive scan of cnt[0..N) -> row_ptr, cursor
__global__ __launch_bounds__(256) void scan_csr(const int* __restrict__ cnt,
                                                int* __restrict__ row_ptr,
                                                int* __restrict__ cursor) {
    __shared__ int part[257];
    const int t = threadIdx.x;
    const int C = (N_NODES + 255) / 256;   // 196
    int beg = t * C, end = min(beg + C, N_NODES);
    int s = 0;
    for (int i = beg; i < end; ++i) s += cnt[i];
    part[t + 1] = s;
    __syncthreads();
    if (t == 0) {
        part[0] = 0;
        for (int i = 1; i <= 256; ++i) part[i] += part[i - 1];
    }
    __syncthreads();
    int base = part[t];
    for (int i = beg; i < end; ++i) {
        row_ptr[i] = base;
        cursor[i]  = base;
        base += cnt[i];
    }
    if (t == 255) row_ptr[N_NODES] = N_EDGES;
}

__global__ void csr_fill(const int* __restrict__ src, const int* __restrict__ dst,
                         int* __restrict__ cursor, int* __restrict__ col) {
    int e = blockIdx.x * blockDim.x + threadIdx.x;
    if (e < N_EDGES) {
        int d = dst[e];
        int p = atomicAdd(&cursor[d], 1);
        col[p] = src[e];
    }
}

// ---------------------------------------------------------------------------
// C[N x 128] = act(X)[N x 128] @ W[128 x 128] * dinv[row]
// BN_IN: act = PReLU(BN(x; sums, gamma, beta, a)) applied while staging X.
template <bool BN_IN>
__global__ __launch_bounds__(256) void gemm128(const float* __restrict__ X,
                                               const float* __restrict__ W,
                                               float* __restrict__ C,
                                               const float* __restrict__ dinv,
                                               const float* __restrict__ sums,
                                               const float* __restrict__ gamma,
                                               const float* __restrict__ beta,
                                               const float* __restrict__ a,
                                               int nrows) {
    __shared__ float Xs[64][128];
    __shared__ float Ws[128][128];
    const int tid  = threadIdx.x;
    const int row0 = blockIdx.x * 64;
    const float invN = 1.0f / (float)N_NODES;

    // stage W: 4096 float4, 16 per thread (coalesced)
    const float4* W4  = (const float4*)W;
    float4*       Ws4 = (float4*)&Ws[0][0];
#pragma unroll
    for (int i = 0; i < 16; ++i) Ws4[tid + 256 * i] = W4[tid + 256 * i];

    // stage X tile: 2048 float4, 8 per thread (coalesced; OOB rows -> 0)
    const float4* X4  = (const float4*)X;
    float4*       Xs4 = (float4*)&Xs[0][0];
#pragma unroll
    for (int i = 0; i < 8; ++i) {
        int idx  = tid + 256 * i;       // float4 index in tile (32 per row)
        int r    = idx >> 5;
        int grow = row0 + r;
        float4 v = make_float4(0.f, 0.f, 0.f, 0.f);
        if (grow < nrows) {
            v = X4[grow * 32 + (idx & 31)];
            if (BN_IN) {
                const int f0 = (idx & 31) * 4;
                const float av = a[0];
                float* vp = (float*)&v;
#pragma unroll
                for (int c = 0; c < 4; ++c) {
                    int f = f0 + c;
                    float mean = sums[f] * invN;
                    float var  = sums[128 + f] * invN - mean * mean;
                    float sc   = rsqrtf(var + BN_EPS) * gamma[f];
                    float y    = (vp[c] - mean) * sc + beta[f];
                    vp[c]      = (y >= 0.f) ? y : av * y;
                }
            }
        }
        Xs4[idx] = v;
    }
    __syncthreads();

    const int rg = tid >> 5;        // 0..7  -> rows r0..r0+7
    const int cg = tid & 31;        // 0..31 -> cols cg + 32*j
    const int r0 = rg * 8;
    float acc[8][4] = {};

    for (int k4 = 0; k4 < 32; ++k4) {
        float4 xa[8];
#pragma unroll
        for (int i = 0; i < 8; ++i) xa[i] = *(const float4*)&Xs[r0 + i][k4 * 4];
#pragma unroll
        for (int kk = 0; kk < 4; ++kk) {
            const int k = k4 * 4 + kk;
            float wb[4];
#pragma unroll
            for (int j = 0; j < 4; ++j) wb[j] = Ws[k][cg + 32 * j];
#pragma unroll
            for (int i = 0; i < 8; ++i) {
                float xv = (kk == 0) ? xa[i].x : (kk == 1) ? xa[i].y
                                               : (kk == 2) ? xa[i].z : xa[i].w;
#pragma unroll
                for (int j = 0; j < 4; ++j) acc[i][j] += xv * wb[j];
            }
        }
    }

#pragma unroll
    for (int i = 0; i < 8; ++i) {
        int grow = row0 + r0 + i;
        if (grow < nrows) {
            float dv = dinv[grow];
#pragma unroll
            for (int j = 0; j < 4; ++j) C[grow * D + cg + 32 * j] = acc[i][j] * dv;
        }
    }
}

// ---------------------------------------------------------------------------
// pull-aggregate: out[d] = dinv[d] * (Σ_{s in in(d)} H'[s] + H'[d])
// 32 lanes (half-wave) per node, float4 per lane; inner loop unrolled x4
// with independent accumulators for memory-level parallelism.
__global__ __launch_bounds__(256) void pull_agg(const float* __restrict__ H,
                                                const int* __restrict__ row_ptr,
                                                const int* __restrict__ col,
                                                const float* __restrict__ dinv,
                                                float* __restrict__ out) {
    const int sub  = threadIdx.x & 31;                                  // lane in group
    const int grp  = (blockIdx.x * blockDim.x + threadIdx.x) >> 5;      // global group
    const int ngrp = (gridDim.x * blockDim.x) >> 5;
    const float4* H4   = (const float4*)H;
    float4*       out4 = (float4*)out;

    for (int d = grp; d < N_NODES; d += ngrp) {
        const int beg = row_ptr[d];
        const int end = row_ptr[d + 1];
        float4 a0 = H4[(size_t)d * 32 + sub];          // self loop
        float4 a1 = make_float4(0.f, 0.f, 0.f, 0.f);
        float4 a2 = make_float4(0.f, 0.f, 0.f, 0.f);
        float4 a3 = make_float4(0.f, 0.f, 0.f, 0.f);
        int j = beg;
        for (; j + 3 < end; j += 4) {
            const int s0 = col[j], s1 = col[j + 1], s2 = col[j + 2], s3 = col[j + 3];
            const float4 v0 = H4[(size_t)s0 * 32 + sub];
            const float4 v1 = H4[(size_t)s1 * 32 + sub];
            const float4 v2 = H4[(size_t)s2 * 32 + sub];
            const float4 v3 = H4[(size_t)s3 * 32 + sub];
            a0.x += v0.x; a0.y += v0.y; a0.z += v0.z; a0.w += v0.w;
            a1.x += v1.x; a1.y += v1.y; a1.z += v1.z; a1.w += v1.w;
            a2.x += v2.x; a2.y += v2.y; a2.z += v2.z; a2.w += v2.w;
            a3.x += v3.x; a3.y += v3.y; a3.z += v3.z; a3.w += v3.w;
        }
        for (; j < end; ++j) {
            const float4 v = H4[(size_t)col[j] * 32 + sub];
            a0.x += v.x; a0.y += v.y; a0.z += v.z; a0.w += v.w;
        }
        const float dv = dinv[d];
        float4 r;
        r.x = ((a0.x + a1.x) + (a2.x + a3.x)) * dv;
        r.y = ((a0.y + a1.y) + (a2.y + a3.y)) * dv;
        r.z = ((a0.z + a1.z) + (a2.z + a3.z)) * dv;
        r.w = ((a0.w + a1.w) + (a2.w + a3.w)) * dv;
        out4[(size_t)d * 32 + sub] = r;
    }
}

// ---------------------------------------------------------------------------
// per-feature sum and sum-of-squares (sums[0..127]=sum, sums[128..255]=sumsq)
__global__ __launch_bounds__(256) void bn_reduce(const float* __restrict__ X,
                                                 float* __restrict__ sums, int n) {
    int f    = threadIdx.x & 127;
    int half = threadIdx.x >> 7;
    float s = 0.f, q = 0.f;
    for (int r = blockIdx.x * 2 + half; r < n; r += gridDim.x * 2) {
        float v = X[r * D + f];
        s += v;
        q += v * v;
    }
    atomicAdd(&sums[f], s);
    atomicAdd(&sums[128 + f], q);
}

// BN (training-mode, biased var) + PReLU, in-place safe
__global__ void bn_prelu(const float* __restrict__ X, const float* __restrict__ sums,
                         const float* __restrict__ gamma, const float* __restrict__ beta,
                         const float* __restrict__ a, float* __restrict__ out, int total,
                         float invN) {
    int idx = blockIdx.x * blockDim.x + threadIdx.x;
    if (idx >= total) return;
    int f      = idx & 127;
    float mean = sums[f] * invN;
    float var  = sums[128 + f] * invN - mean * mean;
    float sc   = rsqrtf(var + BN_EPS) * gamma[f];
    float y    = (X[idx] - mean) * sc + beta[f];
    float av   = a[0];
    out[idx]   = (y >= 0.f) ? y : av * y;
}

// ---------------------------------------------------------------------------
extern "C" void kernel_launch(void* const* d_in, const int* in_sizes, int n_in,
                              void* d_out, int out_size, void* d_ws, size_t ws_size,
                              hipStream_t stream) {
    const float* x      = (const float*)d_in[0];
    const int*   edges  = (const int*)d_in[1];   // [2, E]: src then dst
    const float* W1     = (const float*)d_in[2];
    // b1 = d_in[3] cancels under training-mode BN -> skipped
    const float* gamma1 = (const float*)d_in[4];
    const float* beta1  = (const float*)d_in[5];
    const float* a1     = (const float*)d_in[6];
    const float* W2     = (const float*)d_in[7];
    // b2 = d_in[8] skipped (same reason)
    const float* gamma2 = (const float*)d_in[9];
    const float* beta2  = (const float*)d_in[10];
    const float* a2     = (const float*)d_in[11];

    const int* src = edges;
    const int* dst = edges + N_EDGES;

    float* O = (float*)d_out;                       // [N,128] ping-pong / final
    char*  ws = (char*)d_ws;
    float* A       = (float*)ws;                    // 6.4M floats (25.6 MB)
    ws += (size_t)N_NODES * D * sizeof(float);
    float* dinv    = (float*)ws;  ws += N_NODES * sizeof(float);
    float* sums    = (float*)ws;  ws += 256 * sizeof(float);
    int*   cnt     = (int*)ws;    ws += N_NODES * sizeof(int);
    int*   cursor  = (int*)ws;    ws += N_NODES * sizeof(int);
    int*   row_ptr = (int*)ws;    ws += (N_NODES + 1) * sizeof(int);
    int*   col     = (int*)ws;    ws += (size_t)N_EDGES * sizeof(int);

    const int total  = N_NODES * D;
    const float invN = 1.0f / (float)N_NODES;

    const int eGrid    = (N_EDGES + 255) / 256;
    const int nGrid    = (N_NODES + 255) / 256;
    const int gemmGrid = (N_NODES + 63) / 64;
    const int bnGrid   = (total + 255) / 256;

    // --- CSR + dinv (per launch; d_ws is re-poisoned) ---
    hipMemsetAsync(cnt, 0, N_NODES * sizeof(int), stream);
    deg_count<<<eGrid, 256, 0, stream>>>(dst, cnt);
    finalize_dinv<<<nGrid, 256, 0, stream>>>(cnt, dinv);
    scan_csr<<<1, 256, 0, stream>>>(cnt, row_ptr, cursor);
    csr_fill<<<eGrid, 256, 0, stream>>>(src, dst, cursor, col);

    // --- layer 1 ---
    gemm128<false><<<gemmGrid, 256, 0, stream>>>(x, W1, A, dinv,
                                                 nullptr, nullptr, nullptr, nullptr, N_NODES);
    pull_agg<<<2048, 256, 0, stream>>>(A, row_ptr, col, dinv, O);
    hipMemsetAsync(sums, 0, 256 * sizeof(float), stream);
    bn_reduce<<<512, 256, 0, stream>>>(O, sums, N_NODES);

    // --- layer 2 (BN1+PReLU fused into GEMM2 input staging) ---
    gemm128<true><<<gemmGrid, 256, 0, stream>>>(O, W2, A, dinv,
                                                sums, gamma1, beta1, a1, N_NODES);
    pull_agg<<<2048, 256, 0, stream>>>(A, row_ptr, col, dinv, O);
    hipMemsetAsync(sums, 0, 256 * sizeof(float), stream);
    bn_reduce<<<512, 256, 0, stream>>>(O, sums, N_NODES);
    bn_prelu<<<bnGrid, 256, 0, stream>>>(O, sums, gamma2, beta2, a2, O, total, invN);
}

// Round 4
// 502.731 us; speedup vs baseline: 2.1460x; 1.2430x over previous
//
#include <hip/hip_runtime.h>
#include <hip/hip_bf16.h>

#define N_NODES 50000
#define N_EDGES 800000
#define D 128
#define BN_EPS 1e-5f
#define SCAN_BLOCKS ((N_NODES + 255) / 256)   // 196

// ---------------------------------------------------------------------------
// in-degree count (int atomics)
__global__ void deg_count(const int* __restrict__ dst, int* __restrict__ cnt) {
    int e = blockIdx.x * blockDim.x + threadIdx.x;
    if (e < N_EDGES) atomicAdd(&cnt[dst[e]], 1);
}

// dinv[i] = rsqrt(cnt[i] + 1)   (+1 = self loop)
__global__ void finalize_dinv(const int* __restrict__ cnt, float* __restrict__ dinv) {
    int i = blockIdx.x * blockDim.x + threadIdx.x;
    if (i < N_NODES) dinv[i] = rsqrtf((float)cnt[i] + 1.0f);
}

// ---------------------------------------------------------------------------
// hierarchical exclusive scan of cnt -> row_ptr (3 stages)
// stage 1: per-block (256-elem) local exclusive scan + block total
__global__ __launch_bounds__(256) void scan_local(const int* __restrict__ cnt,
                                                  int* __restrict__ row_ptr,
                                                  int* __restrict__ partials) {
    __shared__ int s[256];
    const int t = threadIdx.x;
    const int i = blockIdx.x * 256 + t;
    int v = (i < N_NODES) ? cnt[i] : 0;
    s[t] = v;
    __syncthreads();
#pragma unroll
    for (int off = 1; off < 256; off <<= 1) {
        int add = (t >= off) ? s[t - off] : 0;
        __syncthreads();
        s[t] += add;
        __syncthreads();
    }
    if (i < N_NODES) row_ptr[i] = s[t] - v;          // local exclusive prefix
    if (t == 255) partials[blockIdx.x] = s[255];     // block total
}

// stage 2: single block scans the 196 partials into exclusive bases (in place)
__global__ __launch_bounds__(256) void scan_partials(int* __restrict__ partials) {
    __shared__ int s[256];
    const int t = threadIdx.x;
    int v = (t < SCAN_BLOCKS) ? partials[t] : 0;
    s[t] = v;
    __syncthreads();
#pragma unroll
    for (int off = 1; off < 256; off <<= 1) {
        int add = (t >= off) ? s[t - off] : 0;
        __syncthreads();
        s[t] += add;
        __syncthreads();
    }
    if (t < SCAN_BLOCKS) partials[t] = s[t] - v;     // exclusive base
}

// stage 3: add base, init cursor, terminate row_ptr
__global__ __launch_bounds__(256) void scan_apply(int* __restrict__ row_ptr,
                                                  const int* __restrict__ partials,
                                                  int* __restrict__ cursor) {
    const int i = blockIdx.x * 256 + threadIdx.x;
    if (i < N_NODES) {
        int r = row_ptr[i] + partials[blockIdx.x];
        row_ptr[i] = r;
        cursor[i]  = r;
    }
    if (i == 0) row_ptr[N_NODES] = N_EDGES;
}

__global__ void csr_fill(const int* __restrict__ src, const int* __restrict__ dst,
                         int* __restrict__ cursor, int* __restrict__ col) {
    int e = blockIdx.x * blockDim.x + threadIdx.x;
    if (e < N_EDGES) {
        int d = dst[e];
        int p = atomicAdd(&cursor[d], 1);
        col[p] = src[e];
    }
}

// ---------------------------------------------------------------------------
// C[N x 128] = act(X)[N x 128] @ W[128 x 128] * dinv[row]
// BN_IN: act = PReLU(BN(x; sums, gamma, beta, a)) applied while staging X.
template <bool BN_IN>
__global__ __launch_bounds__(256) void gemm128(const float* __restrict__ X,
                                               const float* __restrict__ W,
                                               float* __restrict__ C,
                                               const float* __restrict__ dinv,
                                               const float* __restrict__ sums,
                                               const float* __restrict__ gamma,
                                               const float* __restrict__ beta,
                                               const float* __restrict__ a,
                                               int nrows) {
    __shared__ float Xs[64][128];
    __shared__ float Ws[128][128];
    const int tid  = threadIdx.x;
    const int row0 = blockIdx.x * 64;
    const float invN = 1.0f / (float)N_NODES;

    // stage W: 4096 float4, 16 per thread (coalesced)
    const float4* W4  = (const float4*)W;
    float4*       Ws4 = (float4*)&Ws[0][0];
#pragma unroll
    for (int i = 0; i < 16; ++i) Ws4[tid + 256 * i] = W4[tid + 256 * i];

    // stage X tile: 2048 float4, 8 per thread (coalesced; OOB rows -> 0)
    const float4* X4  = (const float4*)X;
    float4*       Xs4 = (float4*)&Xs[0][0];
#pragma unroll
    for (int i = 0; i < 8; ++i) {
        int idx  = tid + 256 * i;       // float4 index in tile (32 per row)
        int r    = idx >> 5;
        int grow = row0 + r;
        float4 v = make_float4(0.f, 0.f, 0.f, 0.f);
        if (grow < nrows) {
            v = X4[grow * 32 + (idx & 31)];
            if (BN_IN) {
                const int f0 = (idx & 31) * 4;
                const float av = a[0];
                float* vp = (float*)&v;
#pragma unroll
                for (int c = 0; c < 4; ++c) {
                    int f = f0 + c;
                    float mean = sums[f] * invN;
                    float var  = sums[128 + f] * invN - mean * mean;
                    float sc   = rsqrtf(var + BN_EPS) * gamma[f];
                    float y    = (vp[c] - mean) * sc + beta[f];
                    vp[c]      = (y >= 0.f) ? y : av * y;
                }
            }
        }
        Xs4[idx] = v;
    }
    __syncthreads();

    const int rg = tid >> 5;        // 0..7  -> rows r0..r0+7
    const int cg = tid & 31;        // 0..31 -> cols cg + 32*j
    const int r0 = rg * 8;
    float acc[8][4] = {};

    for (int k4 = 0; k4 < 32; ++k4) {
        float4 xa[8];
#pragma unroll
        for (int i = 0; i < 8; ++i) xa[i] = *(const float4*)&Xs[r0 + i][k4 * 4];
#pragma unroll
        for (int kk = 0; kk < 4; ++kk) {
            const int k = k4 * 4 + kk;
            float wb[4];
#pragma unroll
            for (int j = 0; j < 4; ++j) wb[j] = Ws[k][cg + 32 * j];
#pragma unroll
            for (int i = 0; i < 8; ++i) {
                float xv = (kk == 0) ? xa[i].x : (kk == 1) ? xa[i].y
                                               : (kk == 2) ? xa[i].z : xa[i].w;
#pragma unroll
                for (int j = 0; j < 4; ++j) acc[i][j] += xv * wb[j];
            }
        }
    }

#pragma unroll
    for (int i = 0; i < 8; ++i) {
        int grow = row0 + r0 + i;
        if (grow < nrows) {
            float dv = dinv[grow];
#pragma unroll
            for (int j = 0; j < 4; ++j) C[grow * D + cg + 32 * j] = acc[i][j] * dv;
        }
    }
}

// ---------------------------------------------------------------------------
// pull-aggregate: out[d] = dinv[d] * (Σ_{s in in(d)} H'[s] + H'[d])
// 32 lanes (half-wave) per node, float4 per lane; inner loop unrolled x4
// with independent accumulators for memory-level parallelism.
__global__ __launch_bounds__(256) void pull_agg(const float* __restrict__ H,
                                                const int* __restrict__ row_ptr,
                                                const int* __restrict__ col,
                                                const float* __restrict__ dinv,
                                                float* __restrict__ out) {
    const int sub  = threadIdx.x & 31;                                  // lane in group
    const int grp  = (blockIdx.x * blockDim.x + threadIdx.x) >> 5;      // global group
    const int ngrp = (gridDim.x * blockDim.x) >> 5;
    const float4* H4   = (const float4*)H;
    float4*       out4 = (float4*)out;

    for (int d = grp; d < N_NODES; d += ngrp) {
        const int beg = row_ptr[d];
        const int end = row_ptr[d + 1];
        float4 a0 = H4[(size_t)d * 32 + sub];          // self loop
        float4 a1 = make_float4(0.f, 0.f, 0.f, 0.f);
        float4 a2 = make_float4(0.f, 0.f, 0.f, 0.f);
        float4 a3 = make_float4(0.f, 0.f, 0.f, 0.f);
        int j = beg;
        for (; j + 3 < end; j += 4) {
            const int s0 = col[j], s1 = col[j + 1], s2 = col[j + 2], s3 = col[j + 3];
            const float4 v0 = H4[(size_t)s0 * 32 + sub];
            const float4 v1 = H4[(size_t)s1 * 32 + sub];
            const float4 v2 = H4[(size_t)s2 * 32 + sub];
            const float4 v3 = H4[(size_t)s3 * 32 + sub];
            a0.x += v0.x; a0.y += v0.y; a0.z += v0.z; a0.w += v0.w;
            a1.x += v1.x; a1.y += v1.y; a1.z += v1.z; a1.w += v1.w;
            a2.x += v2.x; a2.y += v2.y; a2.z += v2.z; a2.w += v2.w;
            a3.x += v3.x; a3.y += v3.y; a3.z += v3.z; a3.w += v3.w;
        }
        for (; j < end; ++j) {
            const float4 v = H4[(size_t)col[j] * 32 + sub];
            a0.x += v.x; a0.y += v.y; a0.z += v.z; a0.w += v.w;
        }
        const float dv = dinv[d];
        float4 r;
        r.x = ((a0.x + a1.x) + (a2.x + a3.x)) * dv;
        r.y = ((a0.y + a1.y) + (a2.y + a3.y)) * dv;
        r.z = ((a0.z + a1.z) + (a2.z + a3.z)) * dv;
        r.w = ((a0.w + a1.w) + (a2.w + a3.w)) * dv;
        out4[(size_t)d * 32 + sub] = r;
    }
}

// ---------------------------------------------------------------------------
// per-feature sum and sum-of-squares (sums[0..127]=sum, sums[128..255]=sumsq)
__global__ __launch_bounds__(256) void bn_reduce(const float* __restrict__ X,
                                                 float* __restrict__ sums, int n) {
    int f    = threadIdx.x & 127;
    int half = threadIdx.x >> 7;
    float s = 0.f, q = 0.f;
    for (int r = blockIdx.x * 2 + half; r < n; r += gridDim.x * 2) {
        float v = X[r * D + f];
        s += v;
        q += v * v;
    }
    atomicAdd(&sums[f], s);
    atomicAdd(&sums[128 + f], q);
}

// BN (training-mode, biased var) + PReLU, in-place safe
__global__ void bn_prelu(const float* __restrict__ X, const float* __restrict__ sums,
                         const float* __restrict__ gamma, const float* __restrict__ beta,
                         const float* __restrict__ a, float* __restrict__ out, int total,
                         float invN) {
    int idx = blockIdx.x * blockDim.x + threadIdx.x;
    if (idx >= total) return;
    int f      = idx & 127;
    float mean = sums[f] * invN;
    float var  = sums[128 + f] * invN - mean * mean;
    float sc   = rsqrtf(var + BN_EPS) * gamma[f];
    float y    = (X[idx] - mean) * sc + beta[f];
    float av   = a[0];
    out[idx]   = (y >= 0.f) ? y : av * y;
}

// ---------------------------------------------------------------------------
extern "C" void kernel_launch(void* const* d_in, const int* in_sizes, int n_in,
                              void* d_out, int out_size, void* d_ws, size_t ws_size,
                              hipStream_t stream) {
    const float* x      = (const float*)d_in[0];
    const int*   edges  = (const int*)d_in[1];   // [2, E]: src then dst
    const float* W1     = (const float*)d_in[2];
    // b1 = d_in[3] cancels under training-mode BN -> skipped
    const float* gamma1 = (const float*)d_in[4];
    const float* beta1  = (const float*)d_in[5];
    const float* a1     = (const float*)d_in[6];
    const float* W2     = (const float*)d_in[7];
    // b2 = d_in[8] skipped (same reason)
    const float* gamma2 = (const float*)d_in[9];
    const float* beta2  = (const float*)d_in[10];
    const float* a2     = (const float*)d_in[11];

    const int* src = edges;
    const int* dst = edges + N_EDGES;

    float* O = (float*)d_out;                       // [N,128] ping-pong / final
    char*  ws = (char*)d_ws;
    float* A        = (float*)ws;                   // 6.4M floats (25.6 MB)
    ws += (size_t)N_NODES * D * sizeof(float);
    float* dinv     = (float*)ws;  ws += N_NODES * sizeof(float);
    float* sums     = (float*)ws;  ws += 256 * sizeof(float);
    int*   cnt      = (int*)ws;    ws += N_NODES * sizeof(int);
    int*   cursor   = (int*)ws;    ws += N_NODES * sizeof(int);
    int*   row_ptr  = (int*)ws;    ws += (N_NODES + 1) * sizeof(int);
    int*   partials = (int*)ws;    ws += 256 * sizeof(int);
    int*   col      = (int*)ws;    ws += (size_t)N_EDGES * sizeof(int);

    const int total  = N_NODES * D;
    const float invN = 1.0f / (float)N_NODES;

    const int eGrid    = (N_EDGES + 255) / 256;
    const int nGrid    = (N_NODES + 255) / 256;
    const int gemmGrid = (N_NODES + 63) / 64;
    const int bnGrid   = (total + 255) / 256;

    // --- CSR + dinv (per launch; d_ws is re-poisoned) ---
    hipMemsetAsync(cnt, 0, N_NODES * sizeof(int), stream);
    deg_count<<<eGrid, 256, 0, stream>>>(dst, cnt);
    finalize_dinv<<<nGrid, 256, 0, stream>>>(cnt, dinv);
    scan_local<<<SCAN_BLOCKS, 256, 0, stream>>>(cnt, row_ptr, partials);
    scan_partials<<<1, 256, 0, stream>>>(partials);
    scan_apply<<<SCAN_BLOCKS, 256, 0, stream>>>(row_ptr, partials, cursor);
    csr_fill<<<eGrid, 256, 0, stream>>>(src, dst, cursor, col);

    // --- layer 1 ---
    gemm128<false><<<gemmGrid, 256, 0, stream>>>(x, W1, A, dinv,
                                                 nullptr, nullptr, nullptr, nullptr, N_NODES);
    pull_agg<<<2048, 256, 0, stream>>>(A, row_ptr, col, dinv, O);
    hipMemsetAsync(sums, 0, 256 * sizeof(float), stream);
    bn_reduce<<<512, 256, 0, stream>>>(O, sums, N_NODES);

    // --- layer 2 (BN1+PReLU fused into GEMM2 input staging) ---
    gemm128<true><<<gemmGrid, 256, 0, stream>>>(O, W2, A, dinv,
                                                sums, gamma1, beta1, a1, N_NODES);
    pull_agg<<<2048, 256, 0, stream>>>(A, row_ptr, col, dinv, O);
    hipMemsetAsync(sums, 0, 256 * sizeof(float), stream);
    bn_reduce<<<512, 256, 0, stream>>>(O, sums, N_NODES);
    bn_prelu<<<bnGrid, 256, 0, stream>>>(O, sums, gamma2, beta2, a2, O, total, invN);
}

// Round 5
// 438.664 us; speedup vs baseline: 2.4594x; 1.1460x over previous
//
#include <hip/hip_runtime.h>
#include <hip/hip_bf16.h>

#define N_NODES 50000
#define N_EDGES 800000
#define D 128
#define BN_EPS 1e-5f
#define SCAN_BLOCKS ((N_NODES + 255) / 256)   // 196
#define GEMM_ROWS 128
#define LDS_PITCH 136                          // 128 + 8 bf16 pad -> uniform banks

typedef short bf16x8 __attribute__((ext_vector_type(8)));
typedef float f32x4  __attribute__((ext_vector_type(4)));

__device__ __forceinline__ unsigned short f2bf(float f) {
    union { float f; unsigned int u; } v; v.f = f;
    unsigned int u = v.u;
    return (unsigned short)((u + 0x7FFF + ((u >> 16) & 1)) >> 16);   // RNE
}

// ---------------------------------------------------------------------------
// in-degree count (int atomics)
__global__ void deg_count(const int* __restrict__ dst, int* __restrict__ cnt) {
    int e = blockIdx.x * blockDim.x + threadIdx.x;
    if (e < N_EDGES) atomicAdd(&cnt[dst[e]], 1);
}

// dinv[i] = rsqrt(cnt[i] + 1)   (+1 = self loop)
__global__ void finalize_dinv(const int* __restrict__ cnt, float* __restrict__ dinv) {
    int i = blockIdx.x * blockDim.x + threadIdx.x;
    if (i < N_NODES) dinv[i] = rsqrtf((float)cnt[i] + 1.0f);
}

// ---------------------------------------------------------------------------
// hierarchical exclusive scan of cnt -> row_ptr (3 stages)
__global__ __launch_bounds__(256) void scan_local(const int* __restrict__ cnt,
                                                  int* __restrict__ row_ptr,
                                                  int* __restrict__ partials) {
    __shared__ int s[256];
    const int t = threadIdx.x;
    const int i = blockIdx.x * 256 + t;
    int v = (i < N_NODES) ? cnt[i] : 0;
    s[t] = v;
    __syncthreads();
#pragma unroll
    for (int off = 1; off < 256; off <<= 1) {
        int add = (t >= off) ? s[t - off] : 0;
        __syncthreads();
        s[t] += add;
        __syncthreads();
    }
    if (i < N_NODES) row_ptr[i] = s[t] - v;
    if (t == 255) partials[blockIdx.x] = s[255];
}

__global__ __launch_bounds__(256) void scan_partials(int* __restrict__ partials) {
    __shared__ int s[256];
    const int t = threadIdx.x;
    int v = (t < SCAN_BLOCKS) ? partials[t] : 0;
    s[t] = v;
    __syncthreads();
#pragma unroll
    for (int off = 1; off < 256; off <<= 1) {
        int add = (t >= off) ? s[t - off] : 0;
        __syncthreads();
        s[t] += add;
        __syncthreads();
    }
    if (t < SCAN_BLOCKS) partials[t] = s[t] - v;
}

__global__ __launch_bounds__(256) void scan_apply(int* __restrict__ row_ptr,
                                                  const int* __restrict__ partials,
                                                  int* __restrict__ cursor) {
    const int i = blockIdx.x * 256 + threadIdx.x;
    if (i < N_NODES) {
        int r = row_ptr[i] + partials[blockIdx.x];
        row_ptr[i] = r;
        cursor[i]  = r;
    }
    if (i == 0) row_ptr[N_NODES] = N_EDGES;
}

__global__ void csr_fill(const int* __restrict__ src, const int* __restrict__ dst,
                         int* __restrict__ cursor, int* __restrict__ col) {
    int e = blockIdx.x * blockDim.x + threadIdx.x;
    if (e < N_EDGES) {
        int d = dst[e];
        int p = atomicAdd(&cursor[d], 1);
        col[p] = src[e];
    }
}

// ---------------------------------------------------------------------------
// Wt[n][k] = bf16(W[k][n]) for both weight matrices (done once per launch)
__global__ __launch_bounds__(256) void w_prep(const float* __restrict__ W1,
                                              const float* __restrict__ W2,
                                              unsigned short* __restrict__ Wt1,
                                              unsigned short* __restrict__ Wt2) {
    int t = blockIdx.x * blockDim.x + threadIdx.x;     // 0..32767
    const float* W        = (t < 16384) ? W1 : W2;
    unsigned short* Wt    = (t < 16384) ? Wt1 : Wt2;
    int u = t & 16383;
    int k = u >> 7, n = u & 127;                       // coalesced read W[k][n]
    Wt[n * 128 + k] = f2bf(W[u]);
}

// ---------------------------------------------------------------------------
// C[N x 128] = act(X) @ W * dinv[row]  via bf16 MFMA (f32 accumulate).
// Wt is pre-transposed bf16 [n][k]. BN_IN: PReLU(BN(x)) applied while staging.
// Block: 256 thr / 4 waves; tile 128 rows x 128 cols; wave w -> cols [32w,32w+32).
// Frag layouts (verified, guide §3): A[m=lane&15][k=q*8+j], B[k=q*8+j][n=lane&15],
// D col=lane&15, row=4q+reg.
template <bool BN_IN>
__global__ __launch_bounds__(256) void gemm_bf16(const float* __restrict__ X,
                                                 const unsigned short* __restrict__ Wt,
                                                 float* __restrict__ C,
                                                 const float* __restrict__ dinv,
                                                 const float* __restrict__ sums,
                                                 const float* __restrict__ gamma,
                                                 const float* __restrict__ beta,
                                                 const float* __restrict__ a,
                                                 int nrows) {
    __shared__ unsigned short As[GEMM_ROWS * LDS_PITCH];   // 34816 B
    __shared__ unsigned short Ws[128 * LDS_PITCH];         // 34816 B
    const int tid  = threadIdx.x;
    const int row0 = blockIdx.x * GEMM_ROWS;
    const float invN = 1.0f / (float)N_NODES;

    // stage Ws: 2048 groups of 8 bf16, coalesced b128 copies
    const bf16x8* Wt8 = (const bf16x8*)Wt;
#pragma unroll
    for (int i = 0; i < 8; ++i) {
        int u  = tid + 256 * i;
        int n  = u >> 4, kg = u & 15;
        *(bf16x8*)&Ws[n * LDS_PITCH + kg * 8] = Wt8[u];
    }

    // stage As: read f32 coalesced, optional BN+PReLU, cvt -> bf16, b64 writes
    const float4* X4 = (const float4*)X;
#pragma unroll
    for (int i = 0; i < 16; ++i) {
        int u    = tid + 256 * i;            // 4096 float4 units
        int r    = u >> 5, kf = u & 31;
        int grow = row0 + r;
        float4 v = make_float4(0.f, 0.f, 0.f, 0.f);
        if (grow < nrows) {
            v = X4[grow * 32 + kf];
            if (BN_IN) {
                const float av = a[0];
                float* vp = (float*)&v;
#pragma unroll
                for (int c = 0; c < 4; ++c) {
                    int f      = kf * 4 + c;
                    float mean = sums[f] * invN;
                    float var  = sums[128 + f] * invN - mean * mean;
                    float sc   = rsqrtf(var + BN_EPS) * gamma[f];
                    float y    = (vp[c] - mean) * sc + beta[f];
                    vp[c]      = (y >= 0.f) ? y : av * y;
                }
            }
        }
        ushort4 p;
        p.x = f2bf(v.x); p.y = f2bf(v.y); p.z = f2bf(v.z); p.w = f2bf(v.w);
        *(ushort4*)&As[r * LDS_PITCH + kf * 4] = p;
    }
    __syncthreads();

    const int wv   = tid >> 6;
    const int lane = tid & 63;
    const int n    = lane & 15;
    const int q    = lane >> 4;
    const int c0   = wv * 32;

    // preload B fragments: 2 col-tiles x 4 k-steps (held in registers)
    bf16x8 bf[4][2];
#pragma unroll
    for (int kb = 0; kb < 4; ++kb)
#pragma unroll
        for (int c = 0; c < 2; ++c)
            bf[kb][c] = *(const bf16x8*)&Ws[(c0 + 16 * c + n) * LDS_PITCH + 32 * kb + 8 * q];

    f32x4 acc[8][2];
    const f32x4 z = {0.f, 0.f, 0.f, 0.f};
#pragma unroll
    for (int rt = 0; rt < 8; ++rt) { acc[rt][0] = z; acc[rt][1] = z; }

#pragma unroll
    for (int kb = 0; kb < 4; ++kb) {
#pragma unroll
        for (int rt = 0; rt < 8; ++rt) {
            bf16x8 af = *(const bf16x8*)&As[(16 * rt + n) * LDS_PITCH + 32 * kb + 8 * q];
            acc[rt][0] = __builtin_amdgcn_mfma_f32_16x16x32_bf16(af, bf[kb][0], acc[rt][0], 0, 0, 0);
            acc[rt][1] = __builtin_amdgcn_mfma_f32_16x16x32_bf16(af, bf[kb][1], acc[rt][1], 0, 0, 0);
        }
    }

    // epilogue: D row = 4q + reg, col = n; scale by dinv[row]
#pragma unroll
    for (int rt = 0; rt < 8; ++rt) {
        int gr0 = row0 + 16 * rt + 4 * q;
#pragma unroll
        for (int r = 0; r < 4; ++r) {
            int gr = gr0 + r;
            if (gr < nrows) {
                float dv = dinv[gr];
                C[gr * D + c0 + n]      = acc[rt][0][r] * dv;
                C[gr * D + c0 + 16 + n] = acc[rt][1][r] * dv;
            }
        }
    }
}

// ---------------------------------------------------------------------------
// pull-aggregate: out[d] = dinv[d] * (Σ_{s in in(d)} H'[s] + H'[d])
__global__ __launch_bounds__(256) void pull_agg(const float* __restrict__ H,
                                                const int* __restrict__ row_ptr,
                                                const int* __restrict__ col,
                                                const float* __restrict__ dinv,
                                                float* __restrict__ out) {
    const int sub  = threadIdx.x & 31;
    const int grp  = (blockIdx.x * blockDim.x + threadIdx.x) >> 5;
    const int ngrp = (gridDim.x * blockDim.x) >> 5;
    const float4* H4   = (const float4*)H;
    float4*       out4 = (float4*)out;

    for (int d = grp; d < N_NODES; d += ngrp) {
        const int beg = row_ptr[d];
        const int end = row_ptr[d + 1];
        float4 a0 = H4[(size_t)d * 32 + sub];          // self loop
        float4 a1 = make_float4(0.f, 0.f, 0.f, 0.f);
        float4 a2 = make_float4(0.f, 0.f, 0.f, 0.f);
        float4 a3 = make_float4(0.f, 0.f, 0.f, 0.f);
        int j = beg;
        for (; j + 3 < end; j += 4) {
            const int s0 = col[j], s1 = col[j + 1], s2 = col[j + 2], s3 = col[j + 3];
            const float4 v0 = H4[(size_t)s0 * 32 + sub];
            const float4 v1 = H4[(size_t)s1 * 32 + sub];
            const float4 v2 = H4[(size_t)s2 * 32 + sub];
            const float4 v3 = H4[(size_t)s3 * 32 + sub];
            a0.x += v0.x; a0.y += v0.y; a0.z += v0.z; a0.w += v0.w;
            a1.x += v1.x; a1.y += v1.y; a1.z += v1.z; a1.w += v1.w;
            a2.x += v2.x; a2.y += v2.y; a2.z += v2.z; a2.w += v2.w;
            a3.x += v3.x; a3.y += v3.y; a3.z += v3.z; a3.w += v3.w;
        }
        for (; j < end; ++j) {
            const float4 v = H4[(size_t)col[j] * 32 + sub];
            a0.x += v.x; a0.y += v.y; a0.z += v.z; a0.w += v.w;
        }
        const float dv = dinv[d];
        float4 r;
        r.x = ((a0.x + a1.x) + (a2.x + a3.x)) * dv;
        r.y = ((a0.y + a1.y) + (a2.y + a3.y)) * dv;
        r.z = ((a0.z + a1.z) + (a2.z + a3.z)) * dv;
        r.w = ((a0.w + a1.w) + (a2.w + a3.w)) * dv;
        out4[(size_t)d * 32 + sub] = r;
    }
}

// ---------------------------------------------------------------------------
// per-feature sum and sum-of-squares (sums[0..127]=sum, sums[128..255]=sumsq)
__global__ __launch_bounds__(256) void bn_reduce(const float* __restrict__ X,
                                                 float* __restrict__ sums, int n) {
    int f    = threadIdx.x & 127;
    int half = threadIdx.x >> 7;
    float s = 0.f, q = 0.f;
    for (int r = blockIdx.x * 2 + half; r < n; r += gridDim.x * 2) {
        float v = X[r * D + f];
        s += v;
        q += v * v;
    }
    atomicAdd(&sums[f], s);
    atomicAdd(&sums[128 + f], q);
}

// BN (training-mode, biased var) + PReLU, in-place safe
__global__ void bn_prelu(const float* __restrict__ X, const float* __restrict__ sums,
                         const float* __restrict__ gamma, const float* __restrict__ beta,
                         const float* __restrict__ a, float* __restrict__ out, int total,
                         float invN) {
    int idx = blockIdx.x * blockDim.x + threadIdx.x;
    if (idx >= total) return;
    int f      = idx & 127;
    float mean = sums[f] * invN;
    float var  = sums[128 + f] * invN - mean * mean;
    float sc   = rsqrtf(var + BN_EPS) * gamma[f];
    float y    = (X[idx] - mean) * sc + beta[f];
    float av   = a[0];
    out[idx]   = (y >= 0.f) ? y : av * y;
}

// ---------------------------------------------------------------------------
extern "C" void kernel_launch(void* const* d_in, const int* in_sizes, int n_in,
                              void* d_out, int out_size, void* d_ws, size_t ws_size,
                              hipStream_t stream) {
    const float* x      = (const float*)d_in[0];
    const int*   edges  = (const int*)d_in[1];   // [2, E]: src then dst
    const float* W1     = (const float*)d_in[2];
    // b1 = d_in[3] cancels under training-mode BN -> skipped
    const float* gamma1 = (const float*)d_in[4];
    const float* beta1  = (const float*)d_in[5];
    const float* a1     = (const float*)d_in[6];
    const float* W2     = (const float*)d_in[7];
    // b2 = d_in[8] skipped (same reason)
    const float* gamma2 = (const float*)d_in[9];
    const float* beta2  = (const float*)d_in[10];
    const float* a2     = (const float*)d_in[11];

    const int* src = edges;
    const int* dst = edges + N_EDGES;

    float* O = (float*)d_out;                       // [N,128] ping-pong / final
    char*  ws = (char*)d_ws;
    float* A        = (float*)ws;                   // 6.4M floats (25.6 MB)
    ws += (size_t)N_NODES * D * sizeof(float);
    float* dinv     = (float*)ws;  ws += N_NODES * sizeof(float);
    float* sums     = (float*)ws;  ws += 256 * sizeof(float);
    int*   cnt      = (int*)ws;    ws += N_NODES * sizeof(int);
    int*   cursor   = (int*)ws;    ws += N_NODES * sizeof(int);
    int*   row_ptr  = (int*)ws;    ws += (N_NODES + 1) * sizeof(int);
    int*   partials = (int*)ws;    ws += 256 * sizeof(int);
    unsigned short* Wt1 = (unsigned short*)ws; ws += 16384 * sizeof(unsigned short);
    unsigned short* Wt2 = (unsigned short*)ws; ws += 16384 * sizeof(unsigned short);
    int*   col      = (int*)ws;    ws += (size_t)N_EDGES * sizeof(int);

    const int total  = N_NODES * D;
    const float invN = 1.0f / (float)N_NODES;

    const int eGrid    = (N_EDGES + 255) / 256;
    const int nGrid    = (N_NODES + 255) / 256;
    const int gemmGrid = (N_NODES + GEMM_ROWS - 1) / GEMM_ROWS;   // 391
    const int bnGrid   = (total + 255) / 256;

    // --- CSR + dinv + weight prep ---
    hipMemsetAsync(cnt, 0, N_NODES * sizeof(int), stream);
    deg_count<<<eGrid, 256, 0, stream>>>(dst, cnt);
    finalize_dinv<<<nGrid, 256, 0, stream>>>(cnt, dinv);
    scan_local<<<SCAN_BLOCKS, 256, 0, stream>>>(cnt, row_ptr, partials);
    scan_partials<<<1, 256, 0, stream>>>(partials);
    scan_apply<<<SCAN_BLOCKS, 256, 0, stream>>>(row_ptr, partials, cursor);
    csr_fill<<<eGrid, 256, 0, stream>>>(src, dst, cursor, col);
    w_prep<<<128, 256, 0, stream>>>(W1, W2, Wt1, Wt2);

    // --- layer 1 ---
    gemm_bf16<false><<<gemmGrid, 256, 0, stream>>>(x, Wt1, A, dinv,
                                                   nullptr, nullptr, nullptr, nullptr, N_NODES);
    pull_agg<<<2048, 256, 0, stream>>>(A, row_ptr, col, dinv, O);
    hipMemsetAsync(sums, 0, 256 * sizeof(float), stream);
    bn_reduce<<<512, 256, 0, stream>>>(O, sums, N_NODES);

    // --- layer 2 (BN1+PReLU fused into GEMM2 input staging) ---
    gemm_bf16<true><<<gemmGrid, 256, 0, stream>>>(O, Wt2, A, dinv,
                                                  sums, gamma1, beta1, a1, N_NODES);
    pull_agg<<<2048, 256, 0, stream>>>(A, row_ptr, col, dinv, O);
    hipMemsetAsync(sums, 0, 256 * sizeof(float), stream);
    bn_reduce<<<512, 256, 0, stream>>>(O, sums, N_NODES);
    bn_prelu<<<bnGrid, 256, 0, stream>>>(O, sums, gamma2, beta2, a2, O, total, invN);
}

// Round 6
// 370.415 us; speedup vs baseline: 2.9125x; 1.1843x over previous
//
#include <hip/hip_runtime.h>
#include <hip/hip_bf16.h>

#define N_NODES 50000
#define N_EDGES 800000
#define D 128
#define BN_EPS 1e-5f
#define SCAN_BLOCKS ((N_NODES + 255) / 256)   // 196
#define GEMM_ROWS 128
#define LDS_PITCH 136                          // 128 + 8 bf16 pad

typedef unsigned short u16;
typedef short bf16x8 __attribute__((ext_vector_type(8)));
typedef float f32x4  __attribute__((ext_vector_type(4)));

__device__ __forceinline__ u16 f2bf(float f) {
    union { float f; unsigned int u; } v; v.f = f;
    unsigned int u = v.u;
    return (u16)((u + 0x7FFF + ((u >> 16) & 1)) >> 16);   // RNE
}
__device__ __forceinline__ float bflo(unsigned int u) {
    union { unsigned int u; float f; } v; v.u = u << 16; return v.f;
}
__device__ __forceinline__ float bfhi(unsigned int u) {
    union { unsigned int u; float f; } v; v.u = u & 0xFFFF0000u; return v.f;
}
__device__ __forceinline__ unsigned int packbf(float a, float b) {
    return (unsigned int)f2bf(a) | ((unsigned int)f2bf(b) << 16);
}

// ---------------------------------------------------------------------------
__global__ void deg_count(const int* __restrict__ dst, int* __restrict__ cnt) {
    int e = blockIdx.x * blockDim.x + threadIdx.x;
    if (e < N_EDGES) atomicAdd(&cnt[dst[e]], 1);
}

// stage 1 scan (+ fused dinv = rsqrt(cnt+1))
__global__ __launch_bounds__(256) void scan_local(const int* __restrict__ cnt,
                                                  int* __restrict__ row_ptr,
                                                  int* __restrict__ partials,
                                                  float* __restrict__ dinv) {
    __shared__ int s[256];
    const int t = threadIdx.x;
    const int i = blockIdx.x * 256 + t;
    int v = (i < N_NODES) ? cnt[i] : 0;
    if (i < N_NODES) dinv[i] = rsqrtf((float)v + 1.0f);
    s[t] = v;
    __syncthreads();
#pragma unroll
    for (int off = 1; off < 256; off <<= 1) {
        int add = (t >= off) ? s[t - off] : 0;
        __syncthreads();
        s[t] += add;
        __syncthreads();
    }
    if (i < N_NODES) row_ptr[i] = s[t] - v;
    if (t == 255) partials[blockIdx.x] = s[255];
}

__global__ __launch_bounds__(256) void scan_partials(int* __restrict__ partials) {
    __shared__ int s[256];
    const int t = threadIdx.x;
    int v = (t < SCAN_BLOCKS) ? partials[t] : 0;
    s[t] = v;
    __syncthreads();
#pragma unroll
    for (int off = 1; off < 256; off <<= 1) {
        int add = (t >= off) ? s[t - off] : 0;
        __syncthreads();
        s[t] += add;
        __syncthreads();
    }
    if (t < SCAN_BLOCKS) partials[t] = s[t] - v;
}

__global__ __launch_bounds__(256) void scan_apply(int* __restrict__ row_ptr,
                                                  const int* __restrict__ partials,
                                                  int* __restrict__ cursor) {
    const int i = blockIdx.x * 256 + threadIdx.x;
    if (i < N_NODES) {
        int r = row_ptr[i] + partials[blockIdx.x];
        row_ptr[i] = r;
        cursor[i]  = r;
    }
    if (i == 0) row_ptr[N_NODES] = N_EDGES;
}

__global__ void csr_fill(const int* __restrict__ src, const int* __restrict__ dst,
                         int* __restrict__ cursor, int* __restrict__ col) {
    int e = blockIdx.x * blockDim.x + threadIdx.x;
    if (e < N_EDGES) {
        int d = dst[e];
        int p = atomicAdd(&cursor[d], 1);
        col[p] = src[e];
    }
}

// ---------------------------------------------------------------------------
// Wt[n][k] = bf16(W[k][n]) for both weight matrices
__global__ __launch_bounds__(256) void w_prep(const float* __restrict__ W1,
                                              const float* __restrict__ W2,
                                              u16* __restrict__ Wt1,
                                              u16* __restrict__ Wt2) {
    int t = blockIdx.x * blockDim.x + threadIdx.x;     // 0..32767
    const float* W = (t < 16384) ? W1 : W2;
    u16* Wt        = (t < 16384) ? Wt1 : Wt2;
    int u = t & 16383;
    int k = u >> 7, n = u & 127;
    Wt[n * 128 + k] = f2bf(W[u]);
}

// ---------------------------------------------------------------------------
// C_bf16[N x 128] = act(X) @ W * dinv[row]  via bf16 MFMA (f32 acc).
// BN_IN=false: X is f32. BN_IN=true: X is bf16 and PReLU(BN(x)) applied in staging.
template <bool BN_IN>
__global__ __launch_bounds__(256) void gemm_bf16(const void* __restrict__ Xv,
                                                 const u16* __restrict__ Wt,
                                                 u16* __restrict__ C,
                                                 const float* __restrict__ dinv,
                                                 const float* __restrict__ sums,
                                                 const float* __restrict__ gamma,
                                                 const float* __restrict__ beta,
                                                 const float* __restrict__ a,
                                                 int nrows) {
    __shared__ u16 As[GEMM_ROWS * LDS_PITCH];   // 34816 B
    __shared__ u16 Ws[128 * LDS_PITCH];         // 34816 B
    const int tid  = threadIdx.x;
    const int row0 = blockIdx.x * GEMM_ROWS;
    const float invN = 1.0f / (float)N_NODES;

    // stage Ws: 2048 groups of 8 bf16
    const bf16x8* Wt8 = (const bf16x8*)Wt;
#pragma unroll
    for (int i = 0; i < 8; ++i) {
        int u = tid + 256 * i;
        int n = u >> 4, kg = u & 15;
        *(bf16x8*)&Ws[n * LDS_PITCH + kg * 8] = Wt8[u];
    }

    if (BN_IN) {
        // bf16 input: 2048 uint4 units (8 bf16 each)
        const uint4* X4 = (const uint4*)Xv;
        const float av = a[0];
#pragma unroll
        for (int i = 0; i < 8; ++i) {
            int u    = tid + 256 * i;
            int r    = u >> 4, kg = u & 15;
            int grow = row0 + r;
            uint4 o = make_uint4(0, 0, 0, 0);
            if (grow < nrows) {
                uint4 v = X4[(size_t)grow * 16 + kg];
                float f[8] = { bflo(v.x), bfhi(v.x), bflo(v.y), bfhi(v.y),
                               bflo(v.z), bfhi(v.z), bflo(v.w), bfhi(v.w) };
#pragma unroll
                for (int c = 0; c < 8; ++c) {
                    int fe     = kg * 8 + c;
                    float mean = sums[fe] * invN;
                    float var  = sums[128 + fe] * invN - mean * mean;
                    float sc   = rsqrtf(var + BN_EPS) * gamma[fe];
                    float y    = (f[c] - mean) * sc + beta[fe];
                    f[c]       = (y >= 0.f) ? y : av * y;
                }
                o.x = packbf(f[0], f[1]); o.y = packbf(f[2], f[3]);
                o.z = packbf(f[4], f[5]); o.w = packbf(f[6], f[7]);
            }
            *(uint4*)&As[r * LDS_PITCH + kg * 8] = o;
        }
    } else {
        // f32 input: 4096 float4 units
        const float4* X4 = (const float4*)Xv;
#pragma unroll
        for (int i = 0; i < 16; ++i) {
            int u    = tid + 256 * i;
            int r    = u >> 5, kf = u & 31;
            int grow = row0 + r;
            float4 v = make_float4(0.f, 0.f, 0.f, 0.f);
            if (grow < nrows) v = X4[(size_t)grow * 32 + kf];
            ushort4 p;
            p.x = f2bf(v.x); p.y = f2bf(v.y); p.z = f2bf(v.z); p.w = f2bf(v.w);
            *(ushort4*)&As[r * LDS_PITCH + kf * 4] = p;
        }
    }
    __syncthreads();

    const int wv   = tid >> 6;
    const int lane = tid & 63;
    const int n    = lane & 15;
    const int q    = lane >> 4;
    const int c0   = wv * 32;

    bf16x8 bfr[4][2];
#pragma unroll
    for (int kb = 0; kb < 4; ++kb)
#pragma unroll
        for (int c = 0; c < 2; ++c)
            bfr[kb][c] = *(const bf16x8*)&Ws[(c0 + 16 * c + n) * LDS_PITCH + 32 * kb + 8 * q];

    f32x4 acc[8][2];
    const f32x4 z = {0.f, 0.f, 0.f, 0.f};
#pragma unroll
    for (int rt = 0; rt < 8; ++rt) { acc[rt][0] = z; acc[rt][1] = z; }

#pragma unroll
    for (int kb = 0; kb < 4; ++kb) {
#pragma unroll
        for (int rt = 0; rt < 8; ++rt) {
            bf16x8 af = *(const bf16x8*)&As[(16 * rt + n) * LDS_PITCH + 32 * kb + 8 * q];
            acc[rt][0] = __builtin_amdgcn_mfma_f32_16x16x32_bf16(af, bfr[kb][0], acc[rt][0], 0, 0, 0);
            acc[rt][1] = __builtin_amdgcn_mfma_f32_16x16x32_bf16(af, bfr[kb][1], acc[rt][1], 0, 0, 0);
        }
    }

    // epilogue: D row = 4q + reg, col = n; scale by dinv[row]; store bf16
#pragma unroll
    for (int rt = 0; rt < 8; ++rt) {
        int gr0 = row0 + 16 * rt + 4 * q;
#pragma unroll
        for (int r = 0; r < 4; ++r) {
            int gr = gr0 + r;
            if (gr < nrows) {
                float dv = dinv[gr];
                C[(size_t)gr * D + c0 + n]      = f2bf(acc[rt][0][r] * dv);
                C[(size_t)gr * D + c0 + 16 + n] = f2bf(acc[rt][1][r] * dv);
            }
        }
    }
}

// ---------------------------------------------------------------------------
// pull-aggregate (bf16 in / bf16 out, f32 accumulate):
// out[d] = dinv[d] * (Σ_{s in in(d)} H[s] + H[d])
// 16 lanes per node; lane sub covers features 8*sub..8*sub+7 via one uint4.
__global__ __launch_bounds__(256) void pull_agg(const u16* __restrict__ H,
                                                const int* __restrict__ row_ptr,
                                                const int* __restrict__ col,
                                                const float* __restrict__ dinv,
                                                u16* __restrict__ out) {
    const int sub  = threadIdx.x & 15;
    const int grp  = (blockIdx.x * blockDim.x + threadIdx.x) >> 4;
    const int ngrp = (gridDim.x * blockDim.x) >> 4;
    const uint4* H4   = (const uint4*)H;
    uint4*       out4 = (uint4*)out;

    for (int d = grp; d < N_NODES; d += ngrp) {
        const int beg = row_ptr[d];
        const int end = row_ptr[d + 1];
        float a0[8], a1[8] = {}, a2[8] = {}, a3[8] = {};
        {
            uint4 v = H4[(size_t)d * 16 + sub];          // self loop
            a0[0] = bflo(v.x); a0[1] = bfhi(v.x); a0[2] = bflo(v.y); a0[3] = bfhi(v.y);
            a0[4] = bflo(v.z); a0[5] = bfhi(v.z); a0[6] = bflo(v.w); a0[7] = bfhi(v.w);
        }
        int j = beg;
        for (; j + 3 < end; j += 4) {
            const int s0 = col[j], s1 = col[j + 1], s2 = col[j + 2], s3 = col[j + 3];
            const uint4 v0 = H4[(size_t)s0 * 16 + sub];
            const uint4 v1 = H4[(size_t)s1 * 16 + sub];
            const uint4 v2 = H4[(size_t)s2 * 16 + sub];
            const uint4 v3 = H4[(size_t)s3 * 16 + sub];
            a0[0] += bflo(v0.x); a0[1] += bfhi(v0.x); a0[2] += bflo(v0.y); a0[3] += bfhi(v0.y);
            a0[4] += bflo(v0.z); a0[5] += bfhi(v0.z); a0[6] += bflo(v0.w); a0[7] += bfhi(v0.w);
            a1[0] += bflo(v1.x); a1[1] += bfhi(v1.x); a1[2] += bflo(v1.y); a1[3] += bfhi(v1.y);
            a1[4] += bflo(v1.z); a1[5] += bfhi(v1.z); a1[6] += bflo(v1.w); a1[7] += bfhi(v1.w);
            a2[0] += bflo(v2.x); a2[1] += bfhi(v2.x); a2[2] += bflo(v2.y); a2[3] += bfhi(v2.y);
            a2[4] += bflo(v2.z); a2[5] += bfhi(v2.z); a2[6] += bflo(v2.w); a2[7] += bfhi(v2.w);
            a3[0] += bflo(v3.x); a3[1] += bfhi(v3.x); a3[2] += bflo(v3.y); a3[3] += bfhi(v3.y);
            a3[4] += bflo(v3.z); a3[5] += bfhi(v3.z); a3[6] += bflo(v3.w); a3[7] += bfhi(v3.w);
        }
        for (; j < end; ++j) {
            const uint4 v = H4[(size_t)col[j] * 16 + sub];
            a0[0] += bflo(v.x); a0[1] += bfhi(v.x); a0[2] += bflo(v.y); a0[3] += bfhi(v.y);
            a0[4] += bflo(v.z); a0[5] += bfhi(v.z); a0[6] += bflo(v.w); a0[7] += bfhi(v.w);
        }
        const float dv = dinv[d];
        float r[8];
#pragma unroll
        for (int c = 0; c < 8; ++c) r[c] = ((a0[c] + a1[c]) + (a2[c] + a3[c])) * dv;
        uint4 o;
        o.x = packbf(r[0], r[1]); o.y = packbf(r[2], r[3]);
        o.z = packbf(r[4], r[5]); o.w = packbf(r[6], r[7]);
        out4[(size_t)d * 16 + sub] = o;
    }
}

// ---------------------------------------------------------------------------
// per-feature sum/sumsq from bf16 X; LDS pre-reduction then atomics
__global__ __launch_bounds__(256) void bn_reduce_bf(const u16* __restrict__ X,
                                                    float* __restrict__ sums, int n) {
    __shared__ float red[256];
    const int fp  = threadIdx.x & 63;   // feature-pair 0..63
    const int rof = threadIdx.x >> 6;   // 0..3
    const unsigned int* X2 = (const unsigned int*)X;
    float s0 = 0.f, q0 = 0.f, s1 = 0.f, q1 = 0.f;
    for (int r = blockIdx.x * 4 + rof; r < n; r += gridDim.x * 4) {
        unsigned int u = X2[(size_t)r * 64 + fp];
        float v0 = bflo(u), v1 = bfhi(u);
        s0 += v0; q0 += v0 * v0; s1 += v1; q1 += v1 * v1;
    }
    red[threadIdx.x] = s0; __syncthreads();
    if (rof == 0) s0 = red[fp] + red[fp + 64] + red[fp + 128] + red[fp + 192];
    __syncthreads(); red[threadIdx.x] = q0; __syncthreads();
    if (rof == 0) q0 = red[fp] + red[fp + 64] + red[fp + 128] + red[fp + 192];
    __syncthreads(); red[threadIdx.x] = s1; __syncthreads();
    if (rof == 0) s1 = red[fp] + red[fp + 64] + red[fp + 128] + red[fp + 192];
    __syncthreads(); red[threadIdx.x] = q1; __syncthreads();
    if (rof == 0) {
        q1 = red[fp] + red[fp + 64] + red[fp + 128] + red[fp + 192];
        int f = fp * 2;
        atomicAdd(&sums[f], s0);       atomicAdd(&sums[128 + f], q0);
        atomicAdd(&sums[f + 1], s1);   atomicAdd(&sums[128 + f + 1], q1);
    }
}

// BN + PReLU, bf16 in -> f32 out (final)
__global__ void bn_prelu_bf(const u16* __restrict__ X, const float* __restrict__ sums,
                            const float* __restrict__ gamma, const float* __restrict__ beta,
                            const float* __restrict__ a, float* __restrict__ out,
                            float invN) {
    int idx = blockIdx.x * blockDim.x + threadIdx.x;     // pair index
    if (idx >= N_NODES * 64) return;
    unsigned int u = ((const unsigned int*)X)[idx];
    int f0 = (idx * 2) & 127;
    float av = a[0];
    float2 o;
    {
        float mean = sums[f0] * invN;
        float var  = sums[128 + f0] * invN - mean * mean;
        float sc   = rsqrtf(var + BN_EPS) * gamma[f0];
        float y    = (bflo(u) - mean) * sc + beta[f0];
        o.x = (y >= 0.f) ? y : av * y;
    }
    {
        int f1 = f0 + 1;
        float mean = sums[f1] * invN;
        float var  = sums[128 + f1] * invN - mean * mean;
        float sc   = rsqrtf(var + BN_EPS) * gamma[f1];
        float y    = (bfhi(u) - mean) * sc + beta[f1];
        o.y = (y >= 0.f) ? y : av * y;
    }
    ((float2*)out)[idx] = o;
}

// ---------------------------------------------------------------------------
extern "C" void kernel_launch(void* const* d_in, const int* in_sizes, int n_in,
                              void* d_out, int out_size, void* d_ws, size_t ws_size,
                              hipStream_t stream) {
    const float* x      = (const float*)d_in[0];
    const int*   edges  = (const int*)d_in[1];   // [2, E]: src then dst
    const float* W1     = (const float*)d_in[2];
    // b1 = d_in[3] cancels under training-mode BN -> skipped
    const float* gamma1 = (const float*)d_in[4];
    const float* beta1  = (const float*)d_in[5];
    const float* a1     = (const float*)d_in[6];
    const float* W2     = (const float*)d_in[7];
    // b2 = d_in[8] skipped (same reason)
    const float* gamma2 = (const float*)d_in[9];
    const float* beta2  = (const float*)d_in[10];
    const float* a2     = (const float*)d_in[11];

    const int* src = edges;
    const int* dst = edges + N_EDGES;

    float* OUT = (float*)d_out;                      // final f32 output
    char* ws = (char*)d_ws;
    u16*   Abf      = (u16*)ws;    ws += (size_t)N_NODES * D * sizeof(u16);   // 12.8 MB
    u16*   Obf      = (u16*)ws;    ws += (size_t)N_NODES * D * sizeof(u16);   // 12.8 MB
    float* dinv     = (float*)ws;  ws += N_NODES * sizeof(float);
    float* sums     = (float*)ws;  ws += 256 * sizeof(float);
    int*   cnt      = (int*)ws;    ws += N_NODES * sizeof(int);
    int*   cursor   = (int*)ws;    ws += N_NODES * sizeof(int);
    int*   row_ptr  = (int*)ws;    ws += (N_NODES + 1) * sizeof(int);
    int*   partials = (int*)ws;    ws += 256 * sizeof(int);
    u16*   Wt1      = (u16*)ws;    ws += 16384 * sizeof(u16);
    u16*   Wt2      = (u16*)ws;    ws += 16384 * sizeof(u16);
    int*   col      = (int*)ws;    ws += (size_t)N_EDGES * sizeof(int);

    const float invN = 1.0f / (float)N_NODES;

    const int eGrid    = (N_EDGES + 255) / 256;
    const int gemmGrid = (N_NODES + GEMM_ROWS - 1) / GEMM_ROWS;   // 391
    const int prGrid   = (N_NODES * 64 + 255) / 256;              // 12500

    // --- CSR + dinv + weight prep ---
    hipMemsetAsync(cnt, 0, N_NODES * sizeof(int), stream);
    deg_count<<<eGrid, 256, 0, stream>>>(dst, cnt);
    scan_local<<<SCAN_BLOCKS, 256, 0, stream>>>(cnt, row_ptr, partials, dinv);
    scan_partials<<<1, 256, 0, stream>>>(partials);
    scan_apply<<<SCAN_BLOCKS, 256, 0, stream>>>(row_ptr, partials, cursor);
    csr_fill<<<eGrid, 256, 0, stream>>>(src, dst, cursor, col);
    w_prep<<<128, 256, 0, stream>>>(W1, W2, Wt1, Wt2);

    // --- layer 1 ---
    gemm_bf16<false><<<gemmGrid, 256, 0, stream>>>(x, Wt1, Abf, dinv,
                                                   nullptr, nullptr, nullptr, nullptr, N_NODES);
    pull_agg<<<2048, 256, 0, stream>>>(Abf, row_ptr, col, dinv, Obf);
    hipMemsetAsync(sums, 0, 256 * sizeof(float), stream);
    bn_reduce_bf<<<512, 256, 0, stream>>>(Obf, sums, N_NODES);

    // --- layer 2 (BN1+PReLU fused into GEMM2 staging) ---
    gemm_bf16<true><<<gemmGrid, 256, 0, stream>>>(Obf, Wt2, Abf, dinv,
                                                  sums, gamma1, beta1, a1, N_NODES);
    pull_agg<<<2048, 256, 0, stream>>>(Abf, row_ptr, col, dinv, Obf);
    hipMemsetAsync(sums, 0, 256 * sizeof(float), stream);
    bn_reduce_bf<<<512, 256, 0, stream>>>(Obf, sums, N_NODES);
    bn_prelu_bf<<<prGrid, 256, 0, stream>>>(Obf, sums, gamma2, beta2, a2, OUT, invN);
}

// Round 7
// 310.105 us; speedup vs baseline: 3.4790x; 1.1945x over previous
//
#include <hip/hip_runtime.h>
#include <hip/hip_bf16.h>

#define N_NODES 50000
#define N_EDGES 800000
#define D 128
#define BN_EPS 1e-5f
#define GEMM_ROWS 128
#define LDS_PITCH 136                          // 128 + 8 bf16 pad

#define BSH 8                                  // bucket = dst >> 8
#define NB 196                                 // ceil(50000/256) buckets
#define TILE 4096                              // edges per scatter block
#define NTILES ((N_EDGES + TILE - 1) / TILE)   // 196
#define REC_CAP 6144                           // max records per bucket (mean 4082, std 64)

typedef unsigned short u16;
typedef short bf16x8 __attribute__((ext_vector_type(8)));
typedef float f32x4  __attribute__((ext_vector_type(4)));

__device__ __forceinline__ u16 f2bf(float f) {
    union { float f; unsigned int u; } v; v.f = f;
    unsigned int u = v.u;
    return (u16)((u + 0x7FFF + ((u >> 16) & 1)) >> 16);   // RNE
}
__device__ __forceinline__ float bflo(unsigned int u) {
    union { unsigned int u; float f; } v; v.u = u << 16; return v.f;
}
__device__ __forceinline__ float bfhi(unsigned int u) {
    union { unsigned int u; float f; } v; v.u = u & 0xFFFF0000u; return v.f;
}
__device__ __forceinline__ unsigned int packbf(float a, float b) {
    return (unsigned int)f2bf(a) | ((unsigned int)f2bf(b) << 16);
}

// ---------------------------------------------------------------------------
// CSR build via LDS-staged bucket sort (no scattered global writes)
// ---------------------------------------------------------------------------
// stage 1: global per-bucket totals (LDS histogram per tile, 1 atomic/bucket/block)
__global__ __launch_bounds__(256) void bucket_hist(const int* __restrict__ dst,
                                                   int* __restrict__ btot) {
    __shared__ int h[256];
    const int t  = threadIdx.x;
    const int e0 = blockIdx.x * TILE;
    h[t] = 0;
    __syncthreads();
#pragma unroll
    for (int i = 0; i < 16; ++i) {
        int e = e0 + t + 256 * i;
        if (e < N_EDGES) atomicAdd(&h[dst[e] >> BSH], 1);
    }
    __syncthreads();
    if (t < NB && h[t] > 0) atomicAdd(&btot[t], h[t]);
}

// stage 2: scan bucket totals -> bases + cursors (1 block)
__global__ __launch_bounds__(256) void bucket_scan(const int* __restrict__ btot,
                                                   int* __restrict__ bbase,
                                                   int* __restrict__ bcur,
                                                   int* __restrict__ row_ptr) {
    __shared__ int s[256];
    const int t = threadIdx.x;
    int v = (t < NB) ? btot[t] : 0;
    s[t] = v;
    __syncthreads();
#pragma unroll
    for (int off = 1; off < 256; off <<= 1) {
        int add = (t >= off) ? s[t - off] : 0;
        __syncthreads();
        s[t] += add;
        __syncthreads();
    }
    if (t < NB) { bbase[t] = s[t] - v; bcur[t] = s[t] - v; }
    if (t == 0) row_ptr[N_NODES] = N_EDGES;
}

// stage 3: bin edges into bucket-contiguous record array, coalesced bursts.
// record = src (u16, low) | dst&255 (bits 16..23)
__global__ __launch_bounds__(256) void bucket_scatter(const int* __restrict__ src,
                                                      const int* __restrict__ dst,
                                                      int* __restrict__ bcur,
                                                      unsigned int* __restrict__ brec) {
    __shared__ int h[256];
    __shared__ int sb[256];
    __shared__ int lbase[256];
    __shared__ int lcur[256];
    __shared__ int gbase[256];
    __shared__ unsigned int  rec[TILE];
    __shared__ unsigned char rbk[TILE];
    const int t  = threadIdx.x;
    const int e0 = blockIdx.x * TILE;
    const int tcount = min(TILE, N_EDGES - e0);

    h[t] = 0;
    __syncthreads();

    unsigned int myrec[16];
    int          myb[16];
#pragma unroll
    for (int i = 0; i < 16; ++i) {
        int e = e0 + t + 256 * i;
        if (e < N_EDGES) {
            unsigned int s_ = (unsigned int)src[e];
            unsigned int d_ = (unsigned int)dst[e];
            int b = (int)(d_ >> BSH);
            myb[i]   = b;
            myrec[i] = s_ | ((d_ & 255u) << 16);
            atomicAdd(&h[b], 1);
        } else myb[i] = -1;
    }
    __syncthreads();
    sb[t] = h[t];
    __syncthreads();
#pragma unroll
    for (int off = 1; off < 256; off <<= 1) {
        int add = (t >= off) ? sb[t - off] : 0;
        __syncthreads();
        sb[t] += add;
        __syncthreads();
    }
    lbase[t] = sb[t] - h[t];
    lcur[t]  = sb[t] - h[t];
    __syncthreads();
    // scatter tile into bucket-sorted LDS order
#pragma unroll
    for (int i = 0; i < 16; ++i) {
        if (myb[i] >= 0) {
            int p = atomicAdd(&lcur[myb[i]], 1);
            rec[p] = myrec[i];
            rbk[p] = (unsigned char)myb[i];
        }
    }
    __syncthreads();
    // allocate one global segment per (bucket, block)
    if (t < NB && h[t] > 0) gbase[t] = atomicAdd(&bcur[t], h[t]);
    __syncthreads();
    // coalesced copy out (records are bucket-contiguous in LDS)
    for (int i = t; i < tcount; i += 256) {
        int b = rbk[i];
        brec[gbase[b] + (i - lbase[b])] = rec[i];
    }
}

// stage 4: per-bucket counting sort -> row_ptr, dinv, col (u16), all coalesced
__global__ __launch_bounds__(256) void bucket_csr(const unsigned int* __restrict__ brec,
                                                  const int* __restrict__ bbase,
                                                  const int* __restrict__ btot,
                                                  int* __restrict__ row_ptr,
                                                  u16* __restrict__ col,
                                                  float* __restrict__ dinv) {
    __shared__ unsigned int rec[REC_CAP];
    __shared__ u16 cls[REC_CAP];
    __shared__ int h[256];
    __shared__ int sb[256];
    __shared__ int lcur[256];
    const int b    = blockIdx.x;
    const int t    = threadIdx.x;
    const int base = bbase[b];
    const int cnt  = min(btot[b], REC_CAP);     // clamp is unreachable in practice
    const int n0   = b << BSH;
    const int nn   = min(256, N_NODES - n0);

    for (int i = t; i < cnt; i += 256) rec[i] = brec[base + i];
    h[t] = 0;
    __syncthreads();
    for (int i = t; i < cnt; i += 256) atomicAdd(&h[(rec[i] >> 16) & 255u], 1);
    __syncthreads();
    sb[t] = h[t];
    __syncthreads();
#pragma unroll
    for (int off = 1; off < 256; off <<= 1) {
        int add = (t >= off) ? sb[t - off] : 0;
        __syncthreads();
        sb[t] += add;
        __syncthreads();
    }
    int excl = sb[t] - h[t];
    lcur[t] = excl;
    if (t < nn) {
        row_ptr[n0 + t] = base + excl;
        dinv[n0 + t]    = rsqrtf((float)h[t] + 1.0f);
    }
    __syncthreads();
    for (int i = t; i < cnt; i += 256) {
        unsigned int r = rec[i];
        int p = atomicAdd(&lcur[(r >> 16) & 255u], 1);
        cls[p] = (u16)(r & 0xFFFFu);
    }
    __syncthreads();
    for (int i = t; i < cnt; i += 256) col[base + i] = cls[i];
}

// ---------------------------------------------------------------------------
// Wt[n][k] = bf16(W[k][n]) for both weight matrices
__global__ __launch_bounds__(256) void w_prep(const float* __restrict__ W1,
                                              const float* __restrict__ W2,
                                              u16* __restrict__ Wt1,
                                              u16* __restrict__ Wt2) {
    int t = blockIdx.x * blockDim.x + threadIdx.x;     // 0..32767
    const float* W = (t < 16384) ? W1 : W2;
    u16* Wt        = (t < 16384) ? Wt1 : Wt2;
    int u = t & 16383;
    int k = u >> 7, n = u & 127;
    Wt[n * 128 + k] = f2bf(W[u]);
}

// ---------------------------------------------------------------------------
// C_bf16[N x 128] = act(X) @ W * dinv[row]  via bf16 MFMA (f32 acc).
// BN_IN=false: X is f32. BN_IN=true: X is bf16 and PReLU(BN(x)) applied in staging.
template <bool BN_IN>
__global__ __launch_bounds__(256) void gemm_bf16(const void* __restrict__ Xv,
                                                 const u16* __restrict__ Wt,
                                                 u16* __restrict__ C,
                                                 const float* __restrict__ dinv,
                                                 const float* __restrict__ sums,
                                                 const float* __restrict__ gamma,
                                                 const float* __restrict__ beta,
                                                 const float* __restrict__ a,
                                                 int nrows) {
    __shared__ u16 As[GEMM_ROWS * LDS_PITCH];   // 34816 B
    __shared__ u16 Ws[128 * LDS_PITCH];         // 34816 B
    const int tid  = threadIdx.x;
    const int row0 = blockIdx.x * GEMM_ROWS;
    const float invN = 1.0f / (float)N_NODES;

    // stage Ws: 2048 groups of 8 bf16
    const bf16x8* Wt8 = (const bf16x8*)Wt;
#pragma unroll
    for (int i = 0; i < 8; ++i) {
        int u = tid + 256 * i;
        int n = u >> 4, kg = u & 15;
        *(bf16x8*)&Ws[n * LDS_PITCH + kg * 8] = Wt8[u];
    }

    if (BN_IN) {
        // bf16 input: 2048 uint4 units (8 bf16 each)
        const uint4* X4 = (const uint4*)Xv;
        const float av = a[0];
#pragma unroll
        for (int i = 0; i < 8; ++i) {
            int u    = tid + 256 * i;
            int r    = u >> 4, kg = u & 15;
            int grow = row0 + r;
            uint4 o = make_uint4(0, 0, 0, 0);
            if (grow < nrows) {
                uint4 v = X4[(size_t)grow * 16 + kg];
                float f[8] = { bflo(v.x), bfhi(v.x), bflo(v.y), bfhi(v.y),
                               bflo(v.z), bfhi(v.z), bflo(v.w), bfhi(v.w) };
#pragma unroll
                for (int c = 0; c < 8; ++c) {
                    int fe     = kg * 8 + c;
                    float mean = sums[fe] * invN;
                    float var  = sums[128 + fe] * invN - mean * mean;
                    float sc   = rsqrtf(var + BN_EPS) * gamma[fe];
                    float y    = (f[c] - mean) * sc + beta[fe];
                    f[c]       = (y >= 0.f) ? y : av * y;
                }
                o.x = packbf(f[0], f[1]); o.y = packbf(f[2], f[3]);
                o.z = packbf(f[4], f[5]); o.w = packbf(f[6], f[7]);
            }
            *(uint4*)&As[r * LDS_PITCH + kg * 8] = o;
        }
    } else {
        // f32 input: 4096 float4 units
        const float4* X4 = (const float4*)Xv;
#pragma unroll
        for (int i = 0; i < 16; ++i) {
            int u    = tid + 256 * i;
            int r    = u >> 5, kf = u & 31;
            int grow = row0 + r;
            float4 v = make_float4(0.f, 0.f, 0.f, 0.f);
            if (grow < nrows) v = X4[(size_t)grow * 32 + kf];
            ushort4 p;
            p.x = f2bf(v.x); p.y = f2bf(v.y); p.z = f2bf(v.z); p.w = f2bf(v.w);
            *(ushort4*)&As[r * LDS_PITCH + kf * 4] = p;
        }
    }
    __syncthreads();

    const int wv   = tid >> 6;
    const int lane = tid & 63;
    const int n    = lane & 15;
    const int q    = lane >> 4;
    const int c0   = wv * 32;

    bf16x8 bfr[4][2];
#pragma unroll
    for (int kb = 0; kb < 4; ++kb)
#pragma unroll
        for (int c = 0; c < 2; ++c)
            bfr[kb][c] = *(const bf16x8*)&Ws[(c0 + 16 * c + n) * LDS_PITCH + 32 * kb + 8 * q];

    f32x4 acc[8][2];
    const f32x4 z = {0.f, 0.f, 0.f, 0.f};
#pragma unroll
    for (int rt = 0; rt < 8; ++rt) { acc[rt][0] = z; acc[rt][1] = z; }

#pragma unroll
    for (int kb = 0; kb < 4; ++kb) {
#pragma unroll
        for (int rt = 0; rt < 8; ++rt) {
            bf16x8 af = *(const bf16x8*)&As[(16 * rt + n) * LDS_PITCH + 32 * kb + 8 * q];
            acc[rt][0] = __builtin_amdgcn_mfma_f32_16x16x32_bf16(af, bfr[kb][0], acc[rt][0], 0, 0, 0);
            acc[rt][1] = __builtin_amdgcn_mfma_f32_16x16x32_bf16(af, bfr[kb][1], acc[rt][1], 0, 0, 0);
        }
    }

    // epilogue: D row = 4q + reg, col = n; scale by dinv[row]; store bf16
#pragma unroll
    for (int rt = 0; rt < 8; ++rt) {
        int gr0 = row0 + 16 * rt + 4 * q;
#pragma unroll
        for (int r = 0; r < 4; ++r) {
            int gr = gr0 + r;
            if (gr < nrows) {
                float dv = dinv[gr];
                C[(size_t)gr * D + c0 + n]      = f2bf(acc[rt][0][r] * dv);
                C[(size_t)gr * D + c0 + 16 + n] = f2bf(acc[rt][1][r] * dv);
            }
        }
    }
}

// ---------------------------------------------------------------------------
// pull-aggregate (bf16 in / bf16 out, f32 accumulate):
// out[d] = dinv[d] * (Σ_{s in in(d)} H[s] + H[d])
// 16 lanes per node; lane sub covers features 8*sub..8*sub+7 via one uint4.
__global__ __launch_bounds__(256) void pull_agg(const u16* __restrict__ H,
                                                const int* __restrict__ row_ptr,
                                                const u16* __restrict__ col,
                                                const float* __restrict__ dinv,
                                                u16* __restrict__ out) {
    const int sub  = threadIdx.x & 15;
    const int grp  = (blockIdx.x * blockDim.x + threadIdx.x) >> 4;
    const int ngrp = (gridDim.x * blockDim.x) >> 4;
    const uint4* H4   = (const uint4*)H;
    uint4*       out4 = (uint4*)out;

    for (int d = grp; d < N_NODES; d += ngrp) {
        const int beg = row_ptr[d];
        const int end = row_ptr[d + 1];
        float a0[8], a1[8] = {}, a2[8] = {}, a3[8] = {};
        {
            uint4 v = H4[(size_t)d * 16 + sub];          // self loop
            a0[0] = bflo(v.x); a0[1] = bfhi(v.x); a0[2] = bflo(v.y); a0[3] = bfhi(v.y);
            a0[4] = bflo(v.z); a0[5] = bfhi(v.z); a0[6] = bflo(v.w); a0[7] = bfhi(v.w);
        }
        int j = beg;
        for (; j + 3 < end; j += 4) {
            const int s0 = col[j], s1 = col[j + 1], s2 = col[j + 2], s3 = col[j + 3];
            const uint4 v0 = H4[(size_t)s0 * 16 + sub];
            const uint4 v1 = H4[(size_t)s1 * 16 + sub];
            const uint4 v2 = H4[(size_t)s2 * 16 + sub];
            const uint4 v3 = H4[(size_t)s3 * 16 + sub];
            a0[0] += bflo(v0.x); a0[1] += bfhi(v0.x); a0[2] += bflo(v0.y); a0[3] += bfhi(v0.y);
            a0[4] += bflo(v0.z); a0[5] += bfhi(v0.z); a0[6] += bflo(v0.w); a0[7] += bfhi(v0.w);
            a1[0] += bflo(v1.x); a1[1] += bfhi(v1.x); a1[2] += bflo(v1.y); a1[3] += bfhi(v1.y);
            a1[4] += bflo(v1.z); a1[5] += bfhi(v1.z); a1[6] += bflo(v1.w); a1[7] += bfhi(v1.w);
            a2[0] += bflo(v2.x); a2[1] += bfhi(v2.x); a2[2] += bflo(v2.y); a2[3] += bfhi(v2.y);
            a2[4] += bflo(v2.z); a2[5] += bfhi(v2.z); a2[6] += bflo(v2.w); a2[7] += bfhi(v2.w);
            a3[0] += bflo(v3.x); a3[1] += bfhi(v3.x); a3[2] += bflo(v3.y); a3[3] += bfhi(v3.y);
            a3[4] += bflo(v3.z); a3[5] += bfhi(v3.z); a3[6] += bflo(v3.w); a3[7] += bfhi(v3.w);
        }
        for (; j < end; ++j) {
            const uint4 v = H4[(size_t)col[j] * 16 + sub];
            a0[0] += bflo(v.x); a0[1] += bfhi(v.x); a0[2] += bflo(v.y); a0[3] += bfhi(v.y);
            a0[4] += bflo(v.z); a0[5] += bfhi(v.z); a0[6] += bflo(v.w); a0[7] += bfhi(v.w);
        }
        const float dv = dinv[d];
        float r[8];
#pragma unroll
        for (int c = 0; c < 8; ++c) r[c] = ((a0[c] + a1[c]) + (a2[c] + a3[c])) * dv;
        uint4 o;
        o.x = packbf(r[0], r[1]); o.y = packbf(r[2], r[3]);
        o.z = packbf(r[4], r[5]); o.w = packbf(r[6], r[7]);
        out4[(size_t)d * 16 + sub] = o;
    }
}

// ---------------------------------------------------------------------------
// per-feature sum/sumsq from bf16 X; LDS pre-reduction then atomics
__global__ __launch_bounds__(256) void bn_reduce_bf(const u16* __restrict__ X,
                                                    float* __restrict__ sums, int n) {
    __shared__ float red[256];
    const int fp  = threadIdx.x & 63;   // feature-pair 0..63
    const int rof = threadIdx.x >> 6;   // 0..3
    const unsigned int* X2 = (const unsigned int*)X;
    float s0 = 0.f, q0 = 0.f, s1 = 0.f, q1 = 0.f;
    for (int r = blockIdx.x * 4 + rof; r < n; r += gridDim.x * 4) {
        unsigned int u = X2[(size_t)r * 64 + fp];
        float v0 = bflo(u), v1 = bfhi(u);
        s0 += v0; q0 += v0 * v0; s1 += v1; q1 += v1 * v1;
    }
    red[threadIdx.x] = s0; __syncthreads();
    if (rof == 0) s0 = red[fp] + red[fp + 64] + red[fp + 128] + red[fp + 192];
    __syncthreads(); red[threadIdx.x] = q0; __syncthreads();
    if (rof == 0) q0 = red[fp] + red[fp + 64] + red[fp + 128] + red[fp + 192];
    __syncthreads(); red[threadIdx.x] = s1; __syncthreads();
    if (rof == 0) s1 = red[fp] + red[fp + 64] + red[fp + 128] + red[fp + 192];
    __syncthreads(); red[threadIdx.x] = q1; __syncthreads();
    if (rof == 0) {
        q1 = red[fp] + red[fp + 64] + red[fp + 128] + red[fp + 192];
        int f = fp * 2;
        atomicAdd(&sums[f], s0);       atomicAdd(&sums[128 + f], q0);
        atomicAdd(&sums[f + 1], s1);   atomicAdd(&sums[128 + f + 1], q1);
    }
}

// BN + PReLU, bf16 in -> f32 out (final)
__global__ void bn_prelu_bf(const u16* __restrict__ X, const float* __restrict__ sums,
                            const float* __restrict__ gamma, const float* __restrict__ beta,
                            const float* __restrict__ a, float* __restrict__ out,
                            float invN) {
    int idx = blockIdx.x * blockDim.x + threadIdx.x;     // pair index
    if (idx >= N_NODES * 64) return;
    unsigned int u = ((const unsigned int*)X)[idx];
    int f0 = (idx * 2) & 127;
    float av = a[0];
    float2 o;
    {
        float mean = sums[f0] * invN;
        float var  = sums[128 + f0] * invN - mean * mean;
        float sc   = rsqrtf(var + BN_EPS) * gamma[f0];
        float y    = (bflo(u) - mean) * sc + beta[f0];
        o.x = (y >= 0.f) ? y : av * y;
    }
    {
        int f1 = f0 + 1;
        float mean = sums[f1] * invN;
        float var  = sums[128 + f1] * invN - mean * mean;
        float sc   = rsqrtf(var + BN_EPS) * gamma[f1];
        float y    = (bfhi(u) - mean) * sc + beta[f1];
        o.y = (y >= 0.f) ? y : av * y;
    }
    ((float2*)out)[idx] = o;
}

// ---------------------------------------------------------------------------
extern "C" void kernel_launch(void* const* d_in, const int* in_sizes, int n_in,
                              void* d_out, int out_size, void* d_ws, size_t ws_size,
                              hipStream_t stream) {
    const float* x      = (const float*)d_in[0];
    const int*   edges  = (const int*)d_in[1];   // [2, E]: src then dst
    const float* W1     = (const float*)d_in[2];
    // b1 = d_in[3] cancels under training-mode BN -> skipped
    const float* gamma1 = (const float*)d_in[4];
    const float* beta1  = (const float*)d_in[5];
    const float* a1     = (const float*)d_in[6];
    const float* W2     = (const float*)d_in[7];
    // b2 = d_in[8] skipped (same reason)
    const float* gamma2 = (const float*)d_in[9];
    const float* beta2  = (const float*)d_in[10];
    const float* a2     = (const float*)d_in[11];

    const int* src = edges;
    const int* dst = edges + N_EDGES;

    float* OUT = (float*)d_out;                      // final f32 output
    char* ws = (char*)d_ws;
    u16*   Abf      = (u16*)ws;    ws += (size_t)N_NODES * D * sizeof(u16);   // 12.8 MB
    u16*   Obf      = (u16*)ws;    ws += (size_t)N_NODES * D * sizeof(u16);   // 12.8 MB
    float* dinv     = (float*)ws;  ws += N_NODES * sizeof(float);
    float* sums     = (float*)ws;  ws += 256 * sizeof(float);
    int*   row_ptr  = (int*)ws;    ws += (N_NODES + 1) * sizeof(int);
    int*   btot     = (int*)ws;    ws += NB * sizeof(int);
    int*   bbase    = (int*)ws;    ws += NB * sizeof(int);
    int*   bcur     = (int*)ws;    ws += NB * sizeof(int);
    unsigned int* brec = (unsigned int*)ws; ws += (size_t)N_EDGES * sizeof(unsigned int);
    u16*   col      = (u16*)ws;    ws += (size_t)N_EDGES * sizeof(u16);
    u16*   Wt1      = (u16*)ws;    ws += 16384 * sizeof(u16);
    u16*   Wt2      = (u16*)ws;    ws += 16384 * sizeof(u16);

    const float invN = 1.0f / (float)N_NODES;
    const int gemmGrid = (N_NODES + GEMM_ROWS - 1) / GEMM_ROWS;   // 391
    const int prGrid   = (N_NODES * 64 + 255) / 256;              // 12500

    // --- CSR build (bucket sort) + dinv + weight prep ---
    hipMemsetAsync(btot, 0, NB * sizeof(int), stream);
    bucket_hist<<<NTILES, 256, 0, stream>>>(dst, btot);
    bucket_scan<<<1, 256, 0, stream>>>(btot, bbase, bcur, row_ptr);
    bucket_scatter<<<NTILES, 256, 0, stream>>>(src, dst, bcur, brec);
    bucket_csr<<<NB, 256, 0, stream>>>(brec, bbase, btot, row_ptr, col, dinv);
    w_prep<<<128, 256, 0, stream>>>(W1, W2, Wt1, Wt2);

    // --- layer 1 ---
    gemm_bf16<false><<<gemmGrid, 256, 0, stream>>>(x, Wt1, Abf, dinv,
                                                   nullptr, nullptr, nullptr, nullptr, N_NODES);
    pull_agg<<<2048, 256, 0, stream>>>(Abf, row_ptr, col, dinv, Obf);
    hipMemsetAsync(sums, 0, 256 * sizeof(float), stream);
    bn_reduce_bf<<<512, 256, 0, stream>>>(Obf, sums, N_NODES);

    // --- layer 2 (BN1+PReLU fused into GEMM2 staging) ---
    gemm_bf16<true><<<gemmGrid, 256, 0, stream>>>(Obf, Wt2, Abf, dinv,
                                                  sums, gamma1, beta1, a1, N_NODES);
    pull_agg<<<2048, 256, 0, stream>>>(Abf, row_ptr, col, dinv, Obf);
    hipMemsetAsync(sums, 0, 256 * sizeof(float), stream);
    bn_reduce_bf<<<512, 256, 0, stream>>>(Obf, sums, N_NODES);
    bn_prelu_bf<<<prGrid, 256, 0, stream>>>(Obf, sums, gamma2, beta2, a2, OUT, invN);
}